// Round 1
// baseline (1120.404 us; speedup 1.0000x reference)
//
#include <hip/hip_runtime.h>

typedef unsigned short u16;
typedef __bf16 bf16x8 __attribute__((ext_vector_type(8)));
typedef float f32x4 __attribute__((ext_vector_type(4)));

#define HDIM 1024
#define VDIM 32000
#define NEXP 8
#define NTOK 2048
#define LSCALE 0.25f

__device__ __forceinline__ float bf2f(u16 v) {
  union { unsigned u; float f; } x; x.u = ((unsigned)v) << 16; return x.f;
}
__device__ __forceinline__ u16 f2bf(float f) {
  union { float f; unsigned u; } x; x.f = f;
  return (u16)((x.u + 0x7fffu + ((x.u >> 16) & 1u)) >> 16);
}
// dual-dtype scalar load (if/else so only one path's load executes)
__device__ __forceinline__ float lde(const void* p, size_t i, int isf32) {
  if (isf32) return ((const float*)p)[i];
  else       return bf2f(((const u16*)p)[i]);
}

// direct global->LDS async copy, 16B per lane. LDS dest must be wave-uniform
// base; HW writes base + lane*16 (guide §5: m97 pattern, 874-912 TF proven).
__device__ __forceinline__ void gload16(const u16* g, u16* l) {
  __builtin_amdgcn_global_load_lds(
      (const __attribute__((address_space(1))) void*)g,
      (__attribute__((address_space(3))) void*)l, 16, 0, 0);
}

// ---------------------------------------------------------------------------
// Dtype detector: sample u16s at even indices of `embedding`. For bf16 data
// these are real bf16 values of N(0,0.02) -> exponent in [87,127] nearly
// always. For fp32 data they are mantissa low-halves -> ~16% in range.
// ---------------------------------------------------------------------------
__global__ __launch_bounds__(256) void detect_dtype(const u16* __restrict__ emb,
                                                    int* __restrict__ flag) {
  __shared__ int cnt;
  int tid = threadIdx.x;
  if (tid == 0) cnt = 0;
  __syncthreads();
  int sane = 0;
  for (int i = tid; i < 1024; i += 256) {
    u16 v = emb[2 * i];
    int ex = (v >> 7) & 0xff;
    sane += (ex >= 87 && ex <= 127) ? 1 : 0;
  }
  atomicAdd(&cnt, sane);
  __syncthreads();
  if (tid == 0) *flag = (cnt < 512) ? 1 : 0;  // 1 = fp32, 0 = bf16
}

// ---------------------------------------------------------------------------
// Transpose W [K x N] cols [ncol0, ncol0+gridDim.y*64) -> WT [(n-ncol0)][k],
// optionally folding LoRA: + scale * sum_r la[h][r]*lb[r][f]. Dual dtype in,
// bf16 out. grid (K/64, cols/64, E), block 256.
// ---------------------------------------------------------------------------
__global__ __launch_bounds__(256) void transpose_lora(
    const void* __restrict__ W, u16* __restrict__ WT,
    const void* __restrict__ la, const void* __restrict__ lb,
    int K, int N, int hasLora, int ncol0, const int* __restrict__ flag) {
  int isf32 = *flag;
  int tk = blockIdx.x * 64;
  int tn = ncol0 + blockIdx.y * 64;      // global col base
  int e  = blockIdx.z;
  __shared__ alignas(16) u16 tile[64][72];
  int tid = threadIdx.x;
  int row = tid >> 2, c0l = (tid & 3) * 16;
  size_t src = (size_t)e * K * N + (size_t)(tk + row) * N + tn + c0l;
  u16 tmp[16];
  if (isf32) {
    const float* Wf = (const float*)W;
#pragma unroll
    for (int j = 0; j < 4; ++j) {
      float4 f = *(const float4*)(Wf + src + j * 4);
      tmp[j * 4 + 0] = f2bf(f.x); tmp[j * 4 + 1] = f2bf(f.y);
      tmp[j * 4 + 2] = f2bf(f.z); tmp[j * 4 + 3] = f2bf(f.w);
    }
  } else {
    const u16* Wh = (const u16*)W;
    *(uint4*)&tmp[0] = *(const uint4*)(Wh + src);
    *(uint4*)&tmp[8] = *(const uint4*)(Wh + src + 8);
  }
  *(uint4*)&tile[row][c0l] = *(uint4*)&tmp[0];
  *(uint4*)&tile[row][c0l + 8] = *(uint4*)&tmp[8];
  __syncthreads();
  int f = tid >> 2;            // local out-row (N dim)
  int h0 = (tid & 3) * 16;     // local out-col chunk (K dim)
  float lbv[4];
  if (hasLora) {
#pragma unroll
    for (int r = 0; r < 4; ++r)
      lbv[r] = lde(lb, (size_t)e * 4 * N + (size_t)r * N + tn + f, isf32);
  }
  u16 outv[16];
#pragma unroll
  for (int i = 0; i < 16; ++i) {
    float x = bf2f(tile[h0 + i][f]);
    if (hasLora) {
      size_t lbase = ((size_t)e * K + tk + h0 + i) * 4;
      float s = 0.f;
#pragma unroll
      for (int r = 0; r < 4; ++r) s += lde(la, lbase + r, isf32) * lbv[r];
      x += LSCALE * s;
    }
    outv[i] = f2bf(x);
  }
  u16* dst = WT + (size_t)e * K * N + (size_t)(blockIdx.y * 64 + f) * K + tk + h0;
  *(uint4*)dst = *(uint4*)&outv[0];
  *(uint4*)(dst + 8) = *(uint4*)&outv[8];
}

// ---------------------------------------------------------------------------
// Embedding gather + gate logits + softmax + top-2 renormalized routing.
// grid: 2048 (one token per block), block 256. Dual dtype.
// ---------------------------------------------------------------------------
__global__ __launch_bounds__(256) void embed_gate(
    const int* __restrict__ x, const void* __restrict__ emb,
    const void* __restrict__ gw, const void* __restrict__ gb,
    u16* __restrict__ h_bf, float* __restrict__ routw,
    const int* __restrict__ flag) {
  int isf32 = *flag;
  int t = blockIdx.x, tid = threadIdx.x;
  __shared__ float hs[HDIM];
  __shared__ float gl[NEXP];
  int idx = x[t];
  if (isf32) {
    const float* er = (const float*)emb + (size_t)idx * HDIM;
    float4 f = ((const float4*)er)[tid];
    u16 h4[4] = { f2bf(f.x), f2bf(f.y), f2bf(f.z), f2bf(f.w) };
    ((uint2*)(h_bf + (size_t)t * HDIM))[tid] = *(uint2*)h4;
    hs[tid * 4 + 0] = f.x; hs[tid * 4 + 1] = f.y;
    hs[tid * 4 + 2] = f.z; hs[tid * 4 + 3] = f.w;
  } else {
    uint2 v = ((const uint2*)((const u16*)emb + (size_t)idx * HDIM))[tid];
    ((uint2*)(h_bf + (size_t)t * HDIM))[tid] = v;
    hs[tid * 4 + 0] = bf2f((u16)(v.x & 0xffffu));
    hs[tid * 4 + 1] = bf2f((u16)(v.x >> 16));
    hs[tid * 4 + 2] = bf2f((u16)(v.y & 0xffffu));
    hs[tid * 4 + 3] = bf2f((u16)(v.y >> 16));
  }
  __syncthreads();
  int wid = tid >> 6, lane = tid & 63;
  int c0 = wid * 2, c1 = c0 + 1;
  float p0 = 0.f, p1 = 0.f;
  for (int i = lane; i < HDIM; i += 64) {
    float hv = hs[i];
    p0 += hv * lde(gw, (size_t)i * 8 + c0, isf32);
    p1 += hv * lde(gw, (size_t)i * 8 + c1, isf32);
  }
#pragma unroll
  for (int off = 32; off; off >>= 1) {
    p0 += __shfl_down(p0, off, 64);
    p1 += __shfl_down(p1, off, 64);
  }
  if (lane == 0) { gl[c0] = p0 + lde(gb, c0, isf32); gl[c1] = p1 + lde(gb, c1, isf32); }
  __syncthreads();
  if (tid == 0) {
    float mx = gl[0];
#pragma unroll
    for (int e = 1; e < NEXP; ++e) mx = fmaxf(mx, gl[e]);
    float pe[NEXP];
#pragma unroll
    for (int e = 0; e < NEXP; ++e) pe[e] = expf(gl[e] - mx);
    int i1 = 0;
#pragma unroll
    for (int e = 1; e < NEXP; ++e) if (pe[e] > pe[i1]) i1 = e;
    int i2 = (i1 == 0) ? 1 : 0;
#pragma unroll
    for (int e = 0; e < NEXP; ++e) if (e != i1 && pe[e] > pe[i2]) i2 = e;
    float s2 = pe[i1] + pe[i2];
    float* rw = routw + (size_t)t * 8;
#pragma unroll
    for (int e = 0; e < NEXP; ++e) rw[e] = 0.f;
    rw[i1] = pe[i1] / s2;
    rw[i2] = pe[i2] / s2;
  }
}

// ---------------------------------------------------------------------------
// Pyramid cache, stage 1: per-expert top-(n/2) selection via 4-level radix
// select on order-preserving 32-bit keys (fp32 bits or bf16<<16; values >=0),
// jax tie rule (value desc, index asc). Writes index list to ws.
// grid: 8, block 256. Dual dtype.
// ---------------------------------------------------------------------------
__global__ __launch_bounds__(256) void cache_select(
    const void* __restrict__ imp, short* __restrict__ listg,
    const int* __restrict__ flag) {
  int isf32 = *flag;
  int e = blockIdx.x, tid = threadIdx.x;
  int n = 2048 - 128 * e, k = n >> 1;
  __shared__ unsigned keys[2048];
  __shared__ int hist[256];
  __shared__ short list[1024];
  __shared__ unsigned s_prefix;
  __shared__ int s_above;
  for (int i = tid; i < n; i += 256) {
    if (isf32) {
      union { float f; unsigned u; } c; c.f = ((const float*)imp)[e * 2048 + i];
      keys[i] = c.u;
    } else {
      keys[i] = ((unsigned)((const u16*)imp)[e * 2048 + i]) << 16;
    }
  }
  __syncthreads();
  unsigned prefix = 0; int above = 0;
  for (int level = 3; level >= 0; --level) {
    hist[tid] = 0;
    __syncthreads();
    for (int i = tid; i < n; i += 256) {
      unsigned kk = keys[i];
      bool m = (level == 3) || ((kk >> ((level + 1) * 8)) == prefix);
      if (m) atomicAdd(&hist[(kk >> (level * 8)) & 255], 1);
    }
    __syncthreads();
    if (tid == 0) {
      int cum = 0, b = 255;
      for (; b > 0; --b) { int h = hist[b]; if (above + cum + h >= k) break; cum += h; }
      s_above = above + cum;
      s_prefix = (prefix << 8) | (unsigned)b;
    }
    __syncthreads();
    prefix = s_prefix; above = s_above;
  }
  // prefix = exact pivot key; above = # keys strictly greater
  if (tid == 0) {
    int need = k - above, c = 0;
    for (int i = 0; i < n; ++i) {
      unsigned kk = keys[i];
      if (kk > prefix) list[c++] = (short)i;
      else if (kk == prefix && need > 0) { list[c++] = (short)i; --need; }
    }
  }
  __syncthreads();
  for (int i = tid; i < k; i += 256) listg[e * 1024 + i] = list[i];
}

// ---------------------------------------------------------------------------
// Pyramid cache, stage 2: mean-pool selected rows over a 64-col slice.
// grid: (8, 16) -> 128 blocks (vs 8 before: was ~1/32 of chip). Dual dtype.
// ---------------------------------------------------------------------------
__global__ __launch_bounds__(256) void cache_pool(
    const void* __restrict__ cv, const short* __restrict__ listg,
    float* __restrict__ mean, const int* __restrict__ flag) {
  int isf32 = *flag;
  int e = blockIdx.x, s = blockIdx.y, tid = threadIdx.x;
  int n = 2048 - 128 * e, k = n >> 1;
  int rg = tid >> 4, ct = tid & 15;  // 16 row-groups x 16 col-threads
  int f0 = s * 64 + ct * 4;
  __shared__ short lists[1024];
  __shared__ float red[16][64];
  for (int i = tid; i < k; i += 256) lists[i] = listg[e * 1024 + i];
  __syncthreads();
  float a0 = 0.f, a1 = 0.f, a2 = 0.f, a3 = 0.f;
  if (isf32) {
    const float* cvf = (const float*)cv;
    for (int j = rg; j < k; j += 16) {
      int row = lists[j];
      float4 vv = *(const float4*)(cvf + ((size_t)e * 2048 + row) * HDIM + f0);
      a0 += vv.x; a1 += vv.y; a2 += vv.z; a3 += vv.w;
    }
  } else {
    const u16* cvh = (const u16*)cv;
    for (int j = rg; j < k; j += 16) {
      int row = lists[j];
      uint2 vv = *(const uint2*)(cvh + ((size_t)e * 2048 + row) * HDIM + f0);
      a0 += bf2f((u16)(vv.x & 0xffffu));
      a1 += bf2f((u16)(vv.x >> 16));
      a2 += bf2f((u16)(vv.y & 0xffffu));
      a3 += bf2f((u16)(vv.y >> 16));
    }
  }
  red[rg][ct * 4 + 0] = a0;
  red[rg][ct * 4 + 1] = a1;
  red[rg][ct * 4 + 2] = a2;
  red[rg][ct * 4 + 3] = a3;
  __syncthreads();
  if (tid < 64) {
    float sm = 0.f;
#pragma unroll
    for (int r = 0; r < 16; ++r) sm += red[r][tid];
    mean[(size_t)e * HDIM + s * 64 + tid] = sm / (float)k;
  }
}

// ---------------------------------------------------------------------------
// Pyramid cache, stage 3: value-LoRA (linear applied to mean) + expert bias.
// ec[e][f] = mean + LSCALE * (mean @ cla) @ clb + eb. grid: 8, block 256.
// ---------------------------------------------------------------------------
__global__ __launch_bounds__(256) void cache_finalize(
    const float* __restrict__ mean, const void* __restrict__ cla,
    const void* __restrict__ clb, const void* __restrict__ eb,
    float* __restrict__ ec, const int* __restrict__ flag) {
  int isf32 = *flag;
  int e = blockIdx.x, tid = threadIdx.x;
  __shared__ float tmp4[4];
  if (tid < 4) tmp4[tid] = 0.f;
  __syncthreads();
  int f0 = tid * 4;
  float m[4];
#pragma unroll
  for (int i = 0; i < 4; ++i) m[i] = mean[(size_t)e * HDIM + f0 + i];
#pragma unroll
  for (int r = 0; r < 4; ++r) {
    float pr = 0.f;
#pragma unroll
    for (int i = 0; i < 4; ++i)
      pr += m[i] * lde(cla, ((size_t)e * HDIM + f0 + i) * 4 + r, isf32);
    atomicAdd(&tmp4[r], pr);
  }
  __syncthreads();
#pragma unroll
  for (int i = 0; i < 4; ++i) {
    int f = f0 + i;
    float add = 0.f;
#pragma unroll
    for (int r = 0; r < 4; ++r)
      add += tmp4[r] * lde(clb, (size_t)e * 4 * HDIM + r * HDIM + f, isf32);
    ec[e * HDIM + f] = m[i] + LSCALE * add + lde(eb, (size_t)e * HDIM + f, isf32);
  }
}

// ---------------------------------------------------------------------------
// Expert GEMMs (dense over 8 experts) with routed-weighted accumulate.
// All operands are internal bf16 ws buffers. BM=64, BN=128, BK=32;
// grid (32, 8), block 256. m97-structure: global_load_lds width-16 staging.
// ---------------------------------------------------------------------------
__global__ __launch_bounds__(256) void gemm_experts(
    const u16* __restrict__ A, const u16* __restrict__ Bt,
    const float* __restrict__ routw, const float* __restrict__ ec,
    u16* __restrict__ outh) {
  const int K = HDIM;
  int m0 = blockIdx.x * 64, n0 = blockIdx.y * 128;
  __shared__ alignas(16) u16 As[64 * 32];
  __shared__ alignas(16) u16 Bs[128 * 32];
  int tid = threadIdx.x, lane = tid & 63, wid = tid >> 6;
  int wm = wid >> 1, wn = wid & 1;
  int q = lane >> 4, lr = lane & 15;
  // staging: wave w covers 16 rows starting at w*16; lane -> (row, col8)
  int srow = wid * 16 + (lane >> 2);
  int scol = (lane & 3) * 8;
  const u16* Ag = A + (size_t)(m0 + srow) * K + scol;
  u16* AsL = As + wid * 16 * 32;   // wave-uniform LDS base
  u16* BsL = Bs + wid * 16 * 32;
  f32x4 fin[2][4];
#pragma unroll
  for (int mi = 0; mi < 2; ++mi)
#pragma unroll
    for (int ni = 0; ni < 4; ++ni) fin[mi][ni] = (f32x4){0.f, 0.f, 0.f, 0.f};

  for (int e = 0; e < NEXP; ++e) {
    const u16* Bg = Bt + (size_t)e * K * HDIM + (size_t)(n0 + srow) * K + scol;
    f32x4 acc[2][4];
#pragma unroll
    for (int mi = 0; mi < 2; ++mi)
#pragma unroll
      for (int ni = 0; ni < 4; ++ni) acc[mi][ni] = (f32x4){0.f, 0.f, 0.f, 0.f};
    for (int kt = 0; kt < K / 32; ++kt) {
      __syncthreads();                     // prior reads of As/Bs complete
      gload16(Ag + kt * 32, AsL);
      gload16(Bg + kt * 32, BsL);
      gload16(Bg + (size_t)64 * K + kt * 32, BsL + 64 * 32);
      __syncthreads();                     // staging drained (vmcnt in barrier)
      bf16x8 af[2], bfr[4];
#pragma unroll
      for (int mi = 0; mi < 2; ++mi)
        af[mi] = *(const bf16x8*)(As + (wm * 32 + mi * 16 + lr) * 32 + q * 8);
#pragma unroll
      for (int ni = 0; ni < 4; ++ni)
        bfr[ni] = *(const bf16x8*)(Bs + (wn * 64 + ni * 16 + lr) * 32 + q * 8);
#pragma unroll
      for (int mi = 0; mi < 2; ++mi)
#pragma unroll
        for (int ni = 0; ni < 4; ++ni)
          acc[mi][ni] = __builtin_amdgcn_mfma_f32_16x16x32_bf16(af[mi], bfr[ni], acc[mi][ni], 0, 0, 0);
    }
    float wr[2][4];
#pragma unroll
    for (int mi = 0; mi < 2; ++mi)
#pragma unroll
      for (int r = 0; r < 4; ++r) {
        int row = m0 + wm * 32 + mi * 16 + q * 4 + r;
        wr[mi][r] = routw[(size_t)row * 8 + e];
      }
#pragma unroll
    for (int ni = 0; ni < 4; ++ni) {
      float ecv = ec[e * HDIM + n0 + wn * 64 + ni * 16 + lr];
#pragma unroll
      for (int mi = 0; mi < 2; ++mi)
#pragma unroll
        for (int r = 0; r < 4; ++r)
          fin[mi][ni][r] += wr[mi][r] * (acc[mi][ni][r] + ecv);
    }
  }
#pragma unroll
  for (int mi = 0; mi < 2; ++mi)
#pragma unroll
    for (int ni = 0; ni < 4; ++ni) {
      int col = n0 + wn * 64 + ni * 16 + lr;
#pragma unroll
      for (int r = 0; r < 4; ++r) {
        int row = m0 + wm * 32 + mi * 16 + q * 4 + r;
        outh[(size_t)row * HDIM + col] = f2bf(fin[mi][ni][r]);
      }
    }
}

// ---------------------------------------------------------------------------
// Vocab GEMM over a column chunk: out[t][n0base+c] = (outh @ vwT_chunk) + vb.
// Output dtype per flag. BM=BN=128, BK=32; block 256. m97-structure staging.
// ---------------------------------------------------------------------------
__global__ __launch_bounds__(256) void gemm_vocab(
    const u16* __restrict__ A, const u16* __restrict__ Bt,
    const void* __restrict__ bias, void* __restrict__ outp,
    int n0base, const int* __restrict__ flag) {
  int isf32 = *flag;
  const int K = HDIM, N = VDIM;
  int m0 = blockIdx.x * 128, n0l = blockIdx.y * 128;
  __shared__ alignas(16) u16 As[128 * 32];
  __shared__ alignas(16) u16 Bs[128 * 32];
  int tid = threadIdx.x, lane = tid & 63, wid = tid >> 6;
  int wm = wid >> 1, wn = wid & 1;
  int q = lane >> 4, lr = lane & 15;
  int srow = wid * 16 + (lane >> 2);
  int scol = (lane & 3) * 8;
  const u16* Ag = A + (size_t)(m0 + srow) * K + scol;
  const u16* Bg = Bt + (size_t)(n0l + srow) * K + scol;
  u16* AsL = As + wid * 16 * 32;
  u16* BsL = Bs + wid * 16 * 32;
  f32x4 acc[4][4];
#pragma unroll
  for (int mi = 0; mi < 4; ++mi)
#pragma unroll
    for (int ni = 0; ni < 4; ++ni) acc[mi][ni] = (f32x4){0.f, 0.f, 0.f, 0.f};

  for (int kt = 0; kt < K / 32; ++kt) {
    __syncthreads();
    gload16(Ag + kt * 32, AsL);
    gload16(Ag + (size_t)64 * K + kt * 32, AsL + 64 * 32);
    gload16(Bg + kt * 32, BsL);
    gload16(Bg + (size_t)64 * K + kt * 32, BsL + 64 * 32);
    __syncthreads();
    bf16x8 af[4], bfr[4];
#pragma unroll
    for (int mi = 0; mi < 4; ++mi)
      af[mi] = *(const bf16x8*)(As + (wm * 64 + mi * 16 + lr) * 32 + q * 8);
#pragma unroll
    for (int ni = 0; ni < 4; ++ni)
      bfr[ni] = *(const bf16x8*)(Bs + (wn * 64 + ni * 16 + lr) * 32 + q * 8);
#pragma unroll
    for (int mi = 0; mi < 4; ++mi)
#pragma unroll
      for (int ni = 0; ni < 4; ++ni)
        acc[mi][ni] = __builtin_amdgcn_mfma_f32_16x16x32_bf16(af[mi], bfr[ni], acc[mi][ni], 0, 0, 0);
  }
#pragma unroll
  for (int ni = 0; ni < 4; ++ni) {
    int col = n0base + n0l + wn * 64 + ni * 16 + lr;
    float vb = lde(bias, col, isf32);
#pragma unroll
    for (int mi = 0; mi < 4; ++mi) {
#pragma unroll
      for (int r = 0; r < 4; ++r) {
        int row = m0 + wm * 64 + mi * 16 + q * 4 + r;
        float val = acc[mi][ni][r] + vb;
        if (isf32) ((float*)outp)[(size_t)row * N + col] = val;
        else       ((u16*)outp)[(size_t)row * N + col] = f2bf(val);
      }
    }
  }
}

// ---------------------------------------------------------------------------
extern "C" void kernel_launch(void* const* d_in, const int* in_sizes, int n_in,
                              void* d_out, int out_size, void* d_ws, size_t ws_size,
                              hipStream_t stream) {
  const int*  x    = (const int*)d_in[0];
  const void* emb  = d_in[1];
  const void* gw   = d_in[2];
  const void* gb   = d_in[3];
  const void* ew   = d_in[4];
  const void* eb   = d_in[5];
  const void* ela  = d_in[6];
  const void* elb  = d_in[7];
  const void* cv   = d_in[8];
  const void* imp  = d_in[9];
  const void* cla  = d_in[10];
  const void* clb  = d_in[11];
  const void* vw   = d_in[12];
  const void* vb   = d_in[13];

  char* ws = (char*)d_ws;
  u16*   WeffT = (u16*)(ws);                 // 8x1024x1024 bf16 = 16,777,216 B
  u16*   h_bf  = (u16*)(ws + 16777216);      // 2048x1024 bf16  =  4,194,304 B
  u16*   outh  = (u16*)(ws + 20971520);      // 2048x1024 bf16  =  4,194,304 B
  float* routw = (float*)(ws + 25165824);    // 2048x8 f32      =     65,536 B
  float* ec    = (float*)(ws + 25231360);    // 8x1024 f32      =     32,768 B
  int*   flag  = (int*)(ws + 25264128);      // 4 B (+pad)
  float* mean  = (float*)(ws + 25264160);    // 8x1024 f32      =     32,768 B
  short* listg = (short*)(ws + 25296928);    // 8x1024 i16      =     16,384 B
  u16*   chunk = (u16*)(ws + 25313312);      // vwT chunk, sized from ws_size

  // chunk columns of vocab_w transposed at a time (128-granular)
  long long avail = (long long)ws_size - 25313312LL;
  long long cc = (avail > 0) ? (avail / (HDIM * 2)) : 0;
  cc &= ~127LL;
  if (cc > VDIM) cc = VDIM;
  if (cc < 128) cc = 128;  // last resort; assumes ws covers the fixed region
  int chunkcols = (int)cc;

  detect_dtype<<<dim3(1), 256, 0, stream>>>((const u16*)emb, flag);
  // fold expert LoRA into weights + transpose -> WeffT [e][f][h]
  transpose_lora<<<dim3(HDIM / 64, HDIM / 64, NEXP), 256, 0, stream>>>(
      ew, WeffT, ela, elb, HDIM, HDIM, 1, 0, flag);
  // embedding gather + gate + top-2 routing
  embed_gate<<<dim3(NTOK), 256, 0, stream>>>(x, emb, gw, gb, h_bf, routw, flag);
  // pyramid cache: select (8 blk) -> pool (128 blk) -> LoRA+bias finalize
  cache_select<<<dim3(NEXP), 256, 0, stream>>>(imp, listg, flag);
  cache_pool<<<dim3(NEXP, 16), 256, 0, stream>>>(cv, listg, mean, flag);
  cache_finalize<<<dim3(NEXP), 256, 0, stream>>>(mean, cla, clb, eb, ec, flag);
  // expert GEMMs + routed weighted combine -> outh bf16
  gemm_experts<<<dim3(NTOK / 64, HDIM / 128), 256, 0, stream>>>(
      h_bf, WeffT, routw, ec, outh);
  // vocab projection in column chunks: transpose chunk then GEMM
  for (int c0 = 0; c0 < VDIM; c0 += chunkcols) {
    int nc = (VDIM - c0 < chunkcols) ? (VDIM - c0) : chunkcols;
    transpose_lora<<<dim3(HDIM / 64, nc / 64, 1), 256, 0, stream>>>(
        vw, chunk, nullptr, nullptr, HDIM, VDIM, 0, c0, flag);
    gemm_vocab<<<dim3(NTOK / 128, nc / 128), 256, 0, stream>>>(
        outh, chunk, vb, d_out, c0, flag);
  }
}

// Round 3
// 921.669 us; speedup vs baseline: 1.2156x; 1.2156x over previous
//
#include <hip/hip_runtime.h>

typedef unsigned short u16;
typedef __bf16 bf16x8 __attribute__((ext_vector_type(8)));
typedef float f32x4 __attribute__((ext_vector_type(4)));

#define HDIM 1024
#define VDIM 32000
#define NEXP 8
#define NTOK 2048
#define LSCALE 0.25f

__device__ __forceinline__ float bf2f(u16 v) {
  union { unsigned u; float f; } x; x.u = ((unsigned)v) << 16; return x.f;
}
__device__ __forceinline__ u16 f2bf(float f) {
  union { float f; unsigned u; } x; x.f = f;
  return (u16)((x.u + 0x7fffu + ((x.u >> 16) & 1u)) >> 16);
}
// dual-dtype scalar load (if/else so only one path's load executes)
__device__ __forceinline__ float lde(const void* p, size_t i, int isf32) {
  if (isf32) return ((const float*)p)[i];
  else       return bf2f(((const u16*)p)[i]);
}

// direct global->LDS async copy, 16B per lane. LDS dest is wave-uniform base;
// HW writes base + lane*16. Global source address IS per-lane (gather legal).
__device__ __forceinline__ void gload16(const u16* g, u16* l) {
  __builtin_amdgcn_global_load_lds(
      (const __attribute__((address_space(1))) void*)g,
      (__attribute__((address_space(3))) void*)l, 16, 0, 0);
}

// ---------------------------------------------------------------------------
// Dtype detector (unchanged, proven).
// ---------------------------------------------------------------------------
__global__ __launch_bounds__(256) void detect_dtype(const u16* __restrict__ emb,
                                                    int* __restrict__ flag) {
  __shared__ int cnt;
  int tid = threadIdx.x;
  if (tid == 0) cnt = 0;
  __syncthreads();
  int sane = 0;
  for (int i = tid; i < 1024; i += 256) {
    u16 v = emb[2 * i];
    int ex = (v >> 7) & 0xff;
    sane += (ex >= 87 && ex <= 127) ? 1 : 0;
  }
  atomicAdd(&cnt, sane);
  __syncthreads();
  if (tid == 0) *flag = (cnt < 512) ? 1 : 0;  // 1 = fp32, 0 = bf16
}

// ---------------------------------------------------------------------------
// Transpose (optionally LoRA-folding) -> bf16 WT. Unchanged, proven.
// ---------------------------------------------------------------------------
__global__ __launch_bounds__(256) void transpose_lora(
    const void* __restrict__ W, u16* __restrict__ WT,
    const void* __restrict__ la, const void* __restrict__ lb,
    int K, int N, int hasLora, int ncol0, const int* __restrict__ flag) {
  int isf32 = *flag;
  int tk = blockIdx.x * 64;
  int tn = ncol0 + blockIdx.y * 64;
  int e  = blockIdx.z;
  __shared__ alignas(16) u16 tile[64][72];
  int tid = threadIdx.x;
  int row = tid >> 2, c0l = (tid & 3) * 16;
  size_t src = (size_t)e * K * N + (size_t)(tk + row) * N + tn + c0l;
  u16 tmp[16];
  if (isf32) {
    const float* Wf = (const float*)W;
#pragma unroll
    for (int j = 0; j < 4; ++j) {
      float4 f = *(const float4*)(Wf + src + j * 4);
      tmp[j * 4 + 0] = f2bf(f.x); tmp[j * 4 + 1] = f2bf(f.y);
      tmp[j * 4 + 2] = f2bf(f.z); tmp[j * 4 + 3] = f2bf(f.w);
    }
  } else {
    const u16* Wh = (const u16*)W;
    *(uint4*)&tmp[0] = *(const uint4*)(Wh + src);
    *(uint4*)&tmp[8] = *(const uint4*)(Wh + src + 8);
  }
  *(uint4*)&tile[row][c0l] = *(uint4*)&tmp[0];
  *(uint4*)&tile[row][c0l + 8] = *(uint4*)&tmp[8];
  __syncthreads();
  int f = tid >> 2;
  int h0 = (tid & 3) * 16;
  float lbv[4];
  if (hasLora) {
#pragma unroll
    for (int r = 0; r < 4; ++r)
      lbv[r] = lde(lb, (size_t)e * 4 * N + (size_t)r * N + tn + f, isf32);
  }
  u16 outv[16];
#pragma unroll
  for (int i = 0; i < 16; ++i) {
    float x = bf2f(tile[h0 + i][f]);
    if (hasLora) {
      size_t lbase = ((size_t)e * K + tk + h0 + i) * 4;
      float s = 0.f;
#pragma unroll
      for (int r = 0; r < 4; ++r) s += lde(la, lbase + r, isf32) * lbv[r];
      x += LSCALE * s;
    }
    outv[i] = f2bf(x);
  }
  u16* dst = WT + (size_t)e * K * N + (size_t)(blockIdx.y * 64 + f) * K + tk + h0;
  *(uint4*)dst = *(uint4*)&outv[0];
  *(uint4*)(dst + 8) = *(uint4*)&outv[8];
}

// ---------------------------------------------------------------------------
// Embedding gather + gate + top-2 routing. Emits compact routing:
// tope[t] = e1 | (e2<<8); topw[t*2+{0,1}] = renormalized weights.
// ---------------------------------------------------------------------------
__global__ __launch_bounds__(256) void embed_gate(
    const int* __restrict__ x, const void* __restrict__ emb,
    const void* __restrict__ gw, const void* __restrict__ gb,
    u16* __restrict__ h_bf, int* __restrict__ tope, float* __restrict__ topw,
    const int* __restrict__ flag) {
  int isf32 = *flag;
  int t = blockIdx.x, tid = threadIdx.x;
  __shared__ float hs[HDIM];
  __shared__ float gl[NEXP];
  int idx = x[t];
  if (isf32) {
    const float* er = (const float*)emb + (size_t)idx * HDIM;
    float4 f = ((const float4*)er)[tid];
    u16 h4[4] = { f2bf(f.x), f2bf(f.y), f2bf(f.z), f2bf(f.w) };
    ((uint2*)(h_bf + (size_t)t * HDIM))[tid] = *(uint2*)h4;
    hs[tid * 4 + 0] = f.x; hs[tid * 4 + 1] = f.y;
    hs[tid * 4 + 2] = f.z; hs[tid * 4 + 3] = f.w;
  } else {
    uint2 v = ((const uint2*)((const u16*)emb + (size_t)idx * HDIM))[tid];
    ((uint2*)(h_bf + (size_t)t * HDIM))[tid] = v;
    hs[tid * 4 + 0] = bf2f((u16)(v.x & 0xffffu));
    hs[tid * 4 + 1] = bf2f((u16)(v.x >> 16));
    hs[tid * 4 + 2] = bf2f((u16)(v.y & 0xffffu));
    hs[tid * 4 + 3] = bf2f((u16)(v.y >> 16));
  }
  __syncthreads();
  int wid = tid >> 6, lane = tid & 63;
  int c0 = wid * 2, c1 = c0 + 1;
  float p0 = 0.f, p1 = 0.f;
  for (int i = lane; i < HDIM; i += 64) {
    float hv = hs[i];
    p0 += hv * lde(gw, (size_t)i * 8 + c0, isf32);
    p1 += hv * lde(gw, (size_t)i * 8 + c1, isf32);
  }
#pragma unroll
  for (int off = 32; off; off >>= 1) {
    p0 += __shfl_down(p0, off, 64);
    p1 += __shfl_down(p1, off, 64);
  }
  if (lane == 0) { gl[c0] = p0 + lde(gb, c0, isf32); gl[c1] = p1 + lde(gb, c1, isf32); }
  __syncthreads();
  if (tid == 0) {
    float mx = gl[0];
#pragma unroll
    for (int e = 1; e < NEXP; ++e) mx = fmaxf(mx, gl[e]);
    float pe[NEXP];
#pragma unroll
    for (int e = 0; e < NEXP; ++e) pe[e] = expf(gl[e] - mx);
    int i1 = 0;
#pragma unroll
    for (int e = 1; e < NEXP; ++e) if (pe[e] > pe[i1]) i1 = e;
    int i2 = (i1 == 0) ? 1 : 0;
#pragma unroll
    for (int e = 0; e < NEXP; ++e) if (e != i1 && pe[e] > pe[i2]) i2 = e;
    float s2 = pe[i1] + pe[i2];
    tope[t] = i1 | (i2 << 8);
    topw[t * 2 + 0] = pe[i1] / s2;
    topw[t * 2 + 1] = pe[i2] / s2;
  }
}

// ---------------------------------------------------------------------------
// Pyramid cache stage 1: radix select (proven) + PARALLEL list build
// (was serial tid==0 over n -> ~LDS-latency-bound). Set equality suffices:
// mean-pool is order-insensitive within tolerance.
// ---------------------------------------------------------------------------
__global__ __launch_bounds__(256) void cache_select(
    const void* __restrict__ imp, short* __restrict__ listg,
    const int* __restrict__ flag) {
  int isf32 = *flag;
  int e = blockIdx.x, tid = threadIdx.x;
  int n = 2048 - 128 * e, k = n >> 1;
  __shared__ unsigned keys[2048];
  __shared__ int hist[256];
  __shared__ short list[1024];
  __shared__ unsigned s_prefix;
  __shared__ int s_above;
  __shared__ int cnt_gt, cnt_tie;
  for (int i = tid; i < n; i += 256) {
    if (isf32) {
      union { float f; unsigned u; } c; c.f = ((const float*)imp)[e * 2048 + i];
      keys[i] = c.u;
    } else {
      keys[i] = ((unsigned)((const u16*)imp)[e * 2048 + i]) << 16;
    }
  }
  if (tid == 0) { cnt_gt = 0; cnt_tie = 0; }
  __syncthreads();
  unsigned prefix = 0; int above = 0;
  for (int level = 3; level >= 0; --level) {
    hist[tid] = 0;
    __syncthreads();
    for (int i = tid; i < n; i += 256) {
      unsigned kk = keys[i];
      bool m = (level == 3) || ((kk >> ((level + 1) * 8)) == prefix);
      if (m) atomicAdd(&hist[(kk >> (level * 8)) & 255], 1);
    }
    __syncthreads();
    if (tid == 0) {
      int cum = 0, b = 255;
      for (; b > 0; --b) { int h = hist[b]; if (above + cum + h >= k) break; cum += h; }
      s_above = above + cum;
      s_prefix = (prefix << 8) | (unsigned)b;
    }
    __syncthreads();
    prefix = s_prefix; above = s_above;
  }
  int need = k - above;
  // parallel: all strictly-greater keys (order irrelevant)
  for (int i = tid; i < n; i += 256) {
    if (keys[i] > prefix) { int p = atomicAdd(&cnt_gt, 1); list[p] = (short)i; }
  }
  __syncthreads();
  // parallel ties: include the `need` smallest indices with key == pivot.
  // rank = # ties at lower index (unique per element -> exactly `need` pass).
  for (int i = tid; i < n; i += 256) {
    if (keys[i] == prefix) {
      int r = 0;
      for (int j = 0; j < i; ++j) r += (keys[j] == prefix) ? 1 : 0;
      if (r < need) { int p = atomicAdd(&cnt_tie, 1); list[above + p] = (short)i; }
    }
  }
  __syncthreads();
  for (int i = tid; i < k; i += 256) listg[e * 1024 + i] = list[i];
}

// ---------------------------------------------------------------------------
// Pyramid cache stage 2: mean-pool selected rows over a 64-col slice.
// ---------------------------------------------------------------------------
__global__ __launch_bounds__(256) void cache_pool(
    const void* __restrict__ cv, const short* __restrict__ listg,
    float* __restrict__ mean, const int* __restrict__ flag) {
  int isf32 = *flag;
  int e = blockIdx.x, s = blockIdx.y, tid = threadIdx.x;
  int n = 2048 - 128 * e, k = n >> 1;
  int rg = tid >> 4, ct = tid & 15;
  int f0 = s * 64 + ct * 4;
  __shared__ short lists[1024];
  __shared__ float red[16][64];
  for (int i = tid; i < k; i += 256) lists[i] = listg[e * 1024 + i];
  __syncthreads();
  float a0 = 0.f, a1 = 0.f, a2 = 0.f, a3 = 0.f;
  if (isf32) {
    const float* cvf = (const float*)cv;
    for (int j = rg; j < k; j += 16) {
      int row = lists[j];
      float4 vv = *(const float4*)(cvf + ((size_t)e * 2048 + row) * HDIM + f0);
      a0 += vv.x; a1 += vv.y; a2 += vv.z; a3 += vv.w;
    }
  } else {
    const u16* cvh = (const u16*)cv;
    for (int j = rg; j < k; j += 16) {
      int row = lists[j];
      uint2 vv = *(const uint2*)(cvh + ((size_t)e * 2048 + row) * HDIM + f0);
      a0 += bf2f((u16)(vv.x & 0xffffu));
      a1 += bf2f((u16)(vv.x >> 16));
      a2 += bf2f((u16)(vv.y & 0xffffu));
      a3 += bf2f((u16)(vv.y >> 16));
    }
  }
  red[rg][ct * 4 + 0] = a0;
  red[rg][ct * 4 + 1] = a1;
  red[rg][ct * 4 + 2] = a2;
  red[rg][ct * 4 + 3] = a3;
  __syncthreads();
  if (tid < 64) {
    float sm = 0.f;
#pragma unroll
    for (int r = 0; r < 16; ++r) sm += red[r][tid];
    mean[(size_t)e * HDIM + s * 64 + tid] = sm / (float)k;
  }
}

// ---------------------------------------------------------------------------
// Pyramid cache stage 3: value-LoRA on mean + expert bias -> ec.
// ---------------------------------------------------------------------------
__global__ __launch_bounds__(256) void cache_finalize(
    const float* __restrict__ mean, const void* __restrict__ cla,
    const void* __restrict__ clb, const void* __restrict__ eb,
    float* __restrict__ ec, const int* __restrict__ flag) {
  int isf32 = *flag;
  int e = blockIdx.x, tid = threadIdx.x;
  __shared__ float tmp4[4];
  if (tid < 4) tmp4[tid] = 0.f;
  __syncthreads();
  int f0 = tid * 4;
  float m[4];
#pragma unroll
  for (int i = 0; i < 4; ++i) m[i] = mean[(size_t)e * HDIM + f0 + i];
#pragma unroll
  for (int r = 0; r < 4; ++r) {
    float pr = 0.f;
#pragma unroll
    for (int i = 0; i < 4; ++i)
      pr += m[i] * lde(cla, ((size_t)e * HDIM + f0 + i) * 4 + r, isf32);
    atomicAdd(&tmp4[r], pr);
  }
  __syncthreads();
#pragma unroll
  for (int i = 0; i < 4; ++i) {
    int f = f0 + i;
    float add = 0.f;
#pragma unroll
    for (int r = 0; r < 4; ++r)
      add += tmp4[r] * lde(clb, (size_t)e * 4 * HDIM + r * HDIM + f, isf32);
    ec[e * HDIM + f] = m[i] + LSCALE * add + lde(eb, (size_t)e * HDIM + f, isf32);
  }
}

// ---------------------------------------------------------------------------
// Build per-expert token lists from compact top-2 routing. grid 8, block 256.
// entry = token | (slot<<15). Order within a list is irrelevant.
// ---------------------------------------------------------------------------
__global__ __launch_bounds__(256) void route_build(
    const int* __restrict__ tope, u16* __restrict__ elist, int* __restrict__ ecnt) {
  int e = blockIdx.x;
  __shared__ int c;
  if (threadIdx.x == 0) c = 0;
  __syncthreads();
  for (int t = threadIdx.x; t < NTOK; t += 256) {
    int pe = tope[t];
    int e1 = pe & 255, e2 = (pe >> 8) & 255;
    if (e1 == e) { int p = atomicAdd(&c, 1); elist[e * NTOK + p] = (u16)t; }
    else if (e2 == e) { int p = atomicAdd(&c, 1); elist[e * NTOK + p] = (u16)(t | 0x8000); }
  }
  __syncthreads();
  if (threadIdx.x == 0) ecnt[e] = c;
}

// ---------------------------------------------------------------------------
// Gathered expert GEMM: only active (token,expert) pairs (top-2 => 4x fewer
// FLOPs than dense). Block = 64 gathered tokens x 128 cols of one expert.
// Writes w*(acc+ec) as f32 into slot buffer (each (token,slot) written once).
// grid (32, 8, 8), early-exit when chunk beyond count.
// ---------------------------------------------------------------------------
__global__ __launch_bounds__(256) void gemm_expert_gather(
    const u16* __restrict__ A, const u16* __restrict__ Bt,
    const float* __restrict__ topw, const u16* __restrict__ elist,
    const int* __restrict__ ecnt, const float* __restrict__ ec,
    float* __restrict__ slot0, float* __restrict__ slot1) {
  const int K = HDIM;
  int mc = blockIdx.x, n0 = blockIdx.y * 128, e = blockIdx.z;
  int cnt = ecnt[e];
  int r0 = mc * 64;
  if (r0 >= cnt) return;
  __shared__ alignas(16) u16 As[64 * 32];
  __shared__ alignas(16) u16 Bs[128 * 32];
  int tid = threadIdx.x, lane = tid & 63, wid = tid >> 6;
  int wm = wid >> 1, wn = wid & 1;
  int q = lane >> 4, lr = lane & 15;
  int srow = wid * 16 + (lane >> 2);
  int scol = (lane & 3) * 8;
  // gathered A row for this lane's staging slot
  int li = r0 + srow; if (li >= cnt) li = r0;       // pad: duplicate row 0 of chunk
  int tokme = elist[e * NTOK + li] & 2047;
  const u16* Ag = A + (size_t)tokme * K + scol;
  const u16* Bg = Bt + (size_t)e * K * HDIM + (size_t)(n0 + srow) * K + scol;
  u16* AsL = As + wid * 16 * 32;
  u16* BsL = Bs + wid * 16 * 32;
  f32x4 acc[2][4];
#pragma unroll
  for (int mi = 0; mi < 2; ++mi)
#pragma unroll
    for (int ni = 0; ni < 4; ++ni) acc[mi][ni] = (f32x4){0.f, 0.f, 0.f, 0.f};
  for (int kt = 0; kt < K / 32; ++kt) {
    __syncthreads();
    gload16(Ag + kt * 32, AsL);
    gload16(Bg + kt * 32, BsL);
    gload16(Bg + (size_t)64 * K + kt * 32, BsL + 64 * 32);
    __syncthreads();
    bf16x8 af[2], bfr[4];
#pragma unroll
    for (int mi = 0; mi < 2; ++mi)
      af[mi] = *(const bf16x8*)(As + (wm * 32 + mi * 16 + lr) * 32 + q * 8);
#pragma unroll
    for (int ni = 0; ni < 4; ++ni)
      bfr[ni] = *(const bf16x8*)(Bs + (wn * 64 + ni * 16 + lr) * 32 + q * 8);
#pragma unroll
    for (int mi = 0; mi < 2; ++mi)
#pragma unroll
      for (int ni = 0; ni < 4; ++ni)
        acc[mi][ni] = __builtin_amdgcn_mfma_f32_16x16x32_bf16(af[mi], bfr[ni], acc[mi][ni], 0, 0, 0);
  }
#pragma unroll
  for (int mi = 0; mi < 2; ++mi) {
#pragma unroll
    for (int r = 0; r < 4; ++r) {
      int lrow = wm * 32 + mi * 16 + q * 4 + r;
      int gi = r0 + lrow;
      if (gi >= cnt) continue;
      int ent = elist[e * NTOK + gi];
      int t2 = ent & 2047, sl = ent >> 15;
      float w = topw[t2 * 2 + sl];
      float* dst = sl ? slot1 : slot0;
#pragma unroll
      for (int ni = 0; ni < 4; ++ni) {
        int col = n0 + wn * 64 + ni * 16 + lr;
        dst[(size_t)t2 * HDIM + col] = w * (acc[mi][ni][r] + ec[e * HDIM + col]);
      }
    }
  }
}

// ---------------------------------------------------------------------------
// outh = f2bf(slot0 + slot1). Every (token,slot) is written (top-2 always).
// ---------------------------------------------------------------------------
__global__ __launch_bounds__(256) void combine_outh(
    const float* __restrict__ s0, const float* __restrict__ s1,
    u16* __restrict__ outh) {
  int i = blockIdx.x * 256 + threadIdx.x;  // one float4-pair per thread
  float4 a = ((const float4*)s0)[i];
  float4 b = ((const float4*)s1)[i];
  u16 o[4] = { f2bf(a.x + b.x), f2bf(a.y + b.y), f2bf(a.z + b.z), f2bf(a.w + b.w) };
  ((uint2*)outh)[i] = *(uint2*)o;
}

// ---------------------------------------------------------------------------
// Vocab GEMM, 256x256 tile, BK=32, 512 threads (2x4 waves, each 128x64 out).
// m97-proven 2-barrier schedule; LDS XOR-swizzle (granule ^= row&3) with
// pre-swizzled global source (rule 21); XCD panel-major block order (T1).
// ---------------------------------------------------------------------------
__global__ __launch_bounds__(512) void gemm_vocab(
    const u16* __restrict__ A, const u16* __restrict__ Bt,
    const void* __restrict__ bias, void* __restrict__ outp,
    int n0base, const int* __restrict__ flag) {
  int isf32 = *flag;
  const int K = HDIM, N = VDIM;
  // XCD-chunked bijective swizzle: grid = nblk*8, per-XCD contiguous panels.
  int nwg = gridDim.x;
  int per = nwg >> 3;                       // nwg % 8 == 0 always (8 m-blocks)
  int newid = (blockIdx.x & 7) * per + (blockIdx.x >> 3);
  int bn = newid >> 3, bm = newid & 7;      // panel-major: 8 m-blocks per panel
  int m0 = bm * 256, n0l = bn * 256;
  __shared__ alignas(16) u16 As[256 * 32];
  __shared__ alignas(16) u16 Bs[256 * 32];
  int tid = threadIdx.x, lane = tid & 63, wid = tid >> 6;
  int wm = wid >> 2, wn = wid & 3;          // 2 x 4 waves
  int q = lane >> 4, lr = lane & 15;
  // staging: per gload16, wave covers 16 rows x 64B. lane -> phys (row,granule);
  // phys granule holds logical granule ^ (row&3)  => source col pre-swizzled.
  int prow = lane >> 2;                      // 0..15
  int lgran = (lane & 3) ^ (prow & 3);       // pre-swizzled source granule
  int srow = wid * 16 + prow;                // 0..127 (strip 0); strip 1 = +128
  const u16* Ag  = A  + (size_t)(m0 + srow) * K + lgran * 8;
  const u16* Ag2 = A  + (size_t)(m0 + 128 + srow) * K + lgran * 8;
  const u16* Bg  = Bt + (size_t)(n0l + srow) * K + lgran * 8;
  const u16* Bg2 = Bt + (size_t)(n0l + 128 + srow) * K + lgran * 8;
  u16* AsL = As + wid * 16 * 32;             // wave-uniform linear dest
  u16* BsL = Bs + wid * 16 * 32;
  f32x4 acc[8][4];
#pragma unroll
  for (int mi = 0; mi < 8; ++mi)
#pragma unroll
    for (int ni = 0; ni < 4; ++ni) acc[mi][ni] = (f32x4){0.f, 0.f, 0.f, 0.f};

  for (int kt = 0; kt < K / 32; ++kt) {
    __syncthreads();
    gload16(Ag  + kt * 32, AsL);
    gload16(Ag2 + kt * 32, AsL + 128 * 32);
    gload16(Bg  + kt * 32, BsL);
    gload16(Bg2 + kt * 32, BsL + 128 * 32);
    __syncthreads();
    bf16x8 af[8], bfr[4];
#pragma unroll
    for (int mi = 0; mi < 8; ++mi) {
      int row = wm * 128 + mi * 16 + lr;
      af[mi] = *(const bf16x8*)(As + row * 32 + ((q ^ (row & 3)) * 8));
    }
#pragma unroll
    for (int ni = 0; ni < 4; ++ni) {
      int row = wn * 64 + ni * 16 + lr;
      bfr[ni] = *(const bf16x8*)(Bs + row * 32 + ((q ^ (row & 3)) * 8));
    }
#pragma unroll
    for (int mi = 0; mi < 8; ++mi)
#pragma unroll
      for (int ni = 0; ni < 4; ++ni)
        acc[mi][ni] = __builtin_amdgcn_mfma_f32_16x16x32_bf16(af[mi], bfr[ni], acc[mi][ni], 0, 0, 0);
  }
#pragma unroll
  for (int ni = 0; ni < 4; ++ni) {
    int col = n0base + n0l + wn * 64 + ni * 16 + lr;
    float vb = lde(bias, col, isf32);
#pragma unroll
    for (int mi = 0; mi < 8; ++mi) {
#pragma unroll
      for (int r = 0; r < 4; ++r) {
        int row = m0 + wm * 128 + mi * 16 + q * 4 + r;
        float val = acc[mi][ni][r] + vb;
        if (isf32) ((float*)outp)[(size_t)row * N + col] = val;
        else       ((u16*)outp)[(size_t)row * N + col] = f2bf(val);
      }
    }
  }
}

// ---------------------------------------------------------------------------
extern "C" void kernel_launch(void* const* d_in, const int* in_sizes, int n_in,
                              void* d_out, int out_size, void* d_ws, size_t ws_size,
                              hipStream_t stream) {
  const int*  x    = (const int*)d_in[0];
  const void* emb  = d_in[1];
  const void* gw   = d_in[2];
  const void* gb   = d_in[3];
  const void* ew   = d_in[4];
  const void* eb   = d_in[5];
  const void* ela  = d_in[6];
  const void* elb  = d_in[7];
  const void* cv   = d_in[8];
  const void* imp  = d_in[9];
  const void* cla  = d_in[10];
  const void* clb  = d_in[11];
  const void* vw   = d_in[12];
  const void* vb   = d_in[13];

  char* ws = (char*)d_ws;
  u16*   WeffT = (u16*)(ws);                  // 16,777,216 B
  u16*   h_bf  = (u16*)(ws + 16777216);       //  4,194,304 B
  u16*   outh  = (u16*)(ws + 20971520);       //  4,194,304 B
  float* ec    = (float*)(ws + 25165824);     //     32,768 B
  int*   flag  = (int*)(ws + 25198592);       //         64 B
  float* mean  = (float*)(ws + 25198656);     //     32,768 B
  short* listg = (short*)(ws + 25231424);     //     16,384 B
  int*   tope  = (int*)(ws + 25247808);       //      8,192 B
  float* topw  = (float*)(ws + 25256000);     //     16,384 B
  u16*   elist = (u16*)(ws + 25272384);       //     32,768 B
  int*   ecnt  = (int*)(ws + 25305152);       //         64 B
  float* slot0 = (float*)(ws + 25305216);     //  8,388,608 B
  float* slot1 = (float*)(ws + 33693824);     //  8,388,608 B
  u16*   chunk = (u16*)(ws + 42082432);       // vocab WT chunk

  // chunk columns (256-granular for the 256-wide gemm tile), cap 16384
  long long avail = (long long)ws_size - 42082432LL;
  long long cc = (avail > 0) ? (avail / (HDIM * 2)) : 0;
  cc &= ~255LL;
  if (cc > 16384) cc = 16384;
  if (cc < 256) cc = 256;  // last resort; ws proven >= ~91 MB by round-0 FETCH math
  int chunkcols = (int)cc;

  detect_dtype<<<dim3(1), 256, 0, stream>>>((const u16*)emb, flag);
  transpose_lora<<<dim3(HDIM / 64, HDIM / 64, NEXP), 256, 0, stream>>>(
      ew, WeffT, ela, elb, HDIM, HDIM, 1, 0, flag);
  embed_gate<<<dim3(NTOK), 256, 0, stream>>>(x, emb, gw, gb, h_bf, tope, topw, flag);
  cache_select<<<dim3(NEXP), 256, 0, stream>>>(imp, listg, flag);
  cache_pool<<<dim3(NEXP, 16), 256, 0, stream>>>(cv, listg, mean, flag);
  cache_finalize<<<dim3(NEXP), 256, 0, stream>>>(mean, cla, clb, eb, ec, flag);
  route_build<<<dim3(NEXP), 256, 0, stream>>>(tope, elist, ecnt);
  gemm_expert_gather<<<dim3(32, 8, NEXP), 256, 0, stream>>>(
      h_bf, WeffT, topw, elist, ecnt, ec, slot0, slot1);
  combine_outh<<<dim3(NTOK * HDIM / 4 / 256), 256, 0, stream>>>(slot0, slot1, outh);
  for (int c0 = 0; c0 < VDIM; c0 += chunkcols) {
    int nc = (VDIM - c0 < chunkcols) ? (VDIM - c0) : chunkcols;
    transpose_lora<<<dim3(HDIM / 64, nc / 64, 1), 256, 0, stream>>>(
        vw, chunk, nullptr, nullptr, HDIM, VDIM, 0, c0, flag);
    gemm_vocab<<<dim3((nc / 256) * 8), 512, 0, stream>>>(
        outh, chunk, vb, d_out, c0, flag);
  }
}

// Round 4
// 840.275 us; speedup vs baseline: 1.3334x; 1.0969x over previous
//
#include <hip/hip_runtime.h>

typedef unsigned short u16;
typedef __bf16 bf16x8 __attribute__((ext_vector_type(8)));
typedef float f32x4 __attribute__((ext_vector_type(4)));

#define HDIM 1024
#define VDIM 32000
#define NEXP 8
#define NTOK 2048
#define LSCALE 0.25f

__device__ __forceinline__ float bf2f(u16 v) {
  union { unsigned u; float f; } x; x.u = ((unsigned)v) << 16; return x.f;
}
__device__ __forceinline__ u16 f2bf(float f) {
  union { float f; unsigned u; } x; x.f = f;
  return (u16)((x.u + 0x7fffu + ((x.u >> 16) & 1u)) >> 16);
}
__device__ __forceinline__ float lde(const void* p, size_t i, int isf32) {
  if (isf32) return ((const float*)p)[i];
  else       return bf2f(((const u16*)p)[i]);
}

// direct global->LDS async copy, 16B/lane. LDS dest wave-uniform base; HW
// writes base + lane*16. Global source IS per-lane (gather/swizzle legal).
__device__ __forceinline__ void gload16(const u16* g, u16* l) {
  __builtin_amdgcn_global_load_lds(
      (const __attribute__((address_space(1))) void*)g,
      (__attribute__((address_space(3))) void*)l, 16, 0, 0);
}

#define SBAR() do { __builtin_amdgcn_s_barrier(); __builtin_amdgcn_sched_barrier(0); } while (0)
#define WAITLGKM() do { asm volatile("s_waitcnt lgkmcnt(0)" ::: "memory"); __builtin_amdgcn_sched_barrier(0); } while (0)
template<int N> __device__ __forceinline__ void waitvm() {
  if constexpr (N == 6) asm volatile("s_waitcnt vmcnt(6)" ::: "memory");
  else if constexpr (N == 2) asm volatile("s_waitcnt vmcnt(2)" ::: "memory");
  else asm volatile("s_waitcnt vmcnt(0)" ::: "memory");
  __builtin_amdgcn_sched_barrier(0);
}

// ---------------------------------------------------------------------------
// Dtype detector (unchanged, proven).
// ---------------------------------------------------------------------------
__global__ __launch_bounds__(256) void detect_dtype(const u16* __restrict__ emb,
                                                    int* __restrict__ flag) {
  __shared__ int cnt;
  int tid = threadIdx.x;
  if (tid == 0) cnt = 0;
  __syncthreads();
  int sane = 0;
  for (int i = tid; i < 1024; i += 256) {
    u16 v = emb[2 * i];
    int ex = (v >> 7) & 0xff;
    sane += (ex >= 87 && ex <= 127) ? 1 : 0;
  }
  atomicAdd(&cnt, sane);
  __syncthreads();
  if (tid == 0) *flag = (cnt < 512) ? 1 : 0;  // 1 = fp32, 0 = bf16
}

// ---------------------------------------------------------------------------
// Transpose (optionally LoRA-folding) -> bf16 WT. Unchanged, proven.
// ---------------------------------------------------------------------------
__global__ __launch_bounds__(256) void transpose_lora(
    const void* __restrict__ W, u16* __restrict__ WT,
    const void* __restrict__ la, const void* __restrict__ lb,
    int K, int N, int hasLora, int ncol0, const int* __restrict__ flag) {
  int isf32 = *flag;
  int tk = blockIdx.x * 64;
  int tn = ncol0 + blockIdx.y * 64;
  int e  = blockIdx.z;
  __shared__ alignas(16) u16 tile[64][72];
  int tid = threadIdx.x;
  int row = tid >> 2, c0l = (tid & 3) * 16;
  size_t src = (size_t)e * K * N + (size_t)(tk + row) * N + tn + c0l;
  u16 tmp[16];
  if (isf32) {
    const float* Wf = (const float*)W;
#pragma unroll
    for (int j = 0; j < 4; ++j) {
      float4 f = *(const float4*)(Wf + src + j * 4);
      tmp[j * 4 + 0] = f2bf(f.x); tmp[j * 4 + 1] = f2bf(f.y);
      tmp[j * 4 + 2] = f2bf(f.z); tmp[j * 4 + 3] = f2bf(f.w);
    }
  } else {
    const u16* Wh = (const u16*)W;
    *(uint4*)&tmp[0] = *(const uint4*)(Wh + src);
    *(uint4*)&tmp[8] = *(const uint4*)(Wh + src + 8);
  }
  *(uint4*)&tile[row][c0l] = *(uint4*)&tmp[0];
  *(uint4*)&tile[row][c0l + 8] = *(uint4*)&tmp[8];
  __syncthreads();
  int f = tid >> 2;
  int h0 = (tid & 3) * 16;
  float lbv[4];
  if (hasLora) {
#pragma unroll
    for (int r = 0; r < 4; ++r)
      lbv[r] = lde(lb, (size_t)e * 4 * N + (size_t)r * N + tn + f, isf32);
  }
  u16 outv[16];
#pragma unroll
  for (int i = 0; i < 16; ++i) {
    float x = bf2f(tile[h0 + i][f]);
    if (hasLora) {
      size_t lbase = ((size_t)e * K + tk + h0 + i) * 4;
      float s = 0.f;
#pragma unroll
      for (int r = 0; r < 4; ++r) s += lde(la, lbase + r, isf32) * lbv[r];
      x += LSCALE * s;
    }
    outv[i] = f2bf(x);
  }
  u16* dst = WT + (size_t)e * K * N + (size_t)(blockIdx.y * 64 + f) * K + tk + h0;
  *(uint4*)dst = *(uint4*)&outv[0];
  *(uint4*)(dst + 8) = *(uint4*)&outv[8];
}

// ---------------------------------------------------------------------------
// Embedding gather + gate + top-2 routing (unchanged, proven).
// ---------------------------------------------------------------------------
__global__ __launch_bounds__(256) void embed_gate(
    const int* __restrict__ x, const void* __restrict__ emb,
    const void* __restrict__ gw, const void* __restrict__ gb,
    u16* __restrict__ h_bf, int* __restrict__ tope, float* __restrict__ topw,
    const int* __restrict__ flag) {
  int isf32 = *flag;
  int t = blockIdx.x, tid = threadIdx.x;
  __shared__ float hs[HDIM];
  __shared__ float gl[NEXP];
  int idx = x[t];
  if (isf32) {
    const float* er = (const float*)emb + (size_t)idx * HDIM;
    float4 f = ((const float4*)er)[tid];
    u16 h4[4] = { f2bf(f.x), f2bf(f.y), f2bf(f.z), f2bf(f.w) };
    ((uint2*)(h_bf + (size_t)t * HDIM))[tid] = *(uint2*)h4;
    hs[tid * 4 + 0] = f.x; hs[tid * 4 + 1] = f.y;
    hs[tid * 4 + 2] = f.z; hs[tid * 4 + 3] = f.w;
  } else {
    uint2 v = ((const uint2*)((const u16*)emb + (size_t)idx * HDIM))[tid];
    ((uint2*)(h_bf + (size_t)t * HDIM))[tid] = v;
    hs[tid * 4 + 0] = bf2f((u16)(v.x & 0xffffu));
    hs[tid * 4 + 1] = bf2f((u16)(v.x >> 16));
    hs[tid * 4 + 2] = bf2f((u16)(v.y & 0xffffu));
    hs[tid * 4 + 3] = bf2f((u16)(v.y >> 16));
  }
  __syncthreads();
  int wid = tid >> 6, lane = tid & 63;
  int c0 = wid * 2, c1 = c0 + 1;
  float p0 = 0.f, p1 = 0.f;
  for (int i = lane; i < HDIM; i += 64) {
    float hv = hs[i];
    p0 += hv * lde(gw, (size_t)i * 8 + c0, isf32);
    p1 += hv * lde(gw, (size_t)i * 8 + c1, isf32);
  }
#pragma unroll
  for (int off = 32; off; off >>= 1) {
    p0 += __shfl_down(p0, off, 64);
    p1 += __shfl_down(p1, off, 64);
  }
  if (lane == 0) { gl[c0] = p0 + lde(gb, c0, isf32); gl[c1] = p1 + lde(gb, c1, isf32); }
  __syncthreads();
  if (tid == 0) {
    float mx = gl[0];
#pragma unroll
    for (int e = 1; e < NEXP; ++e) mx = fmaxf(mx, gl[e]);
    float pe[NEXP];
#pragma unroll
    for (int e = 0; e < NEXP; ++e) pe[e] = expf(gl[e] - mx);
    int i1 = 0;
#pragma unroll
    for (int e = 1; e < NEXP; ++e) if (pe[e] > pe[i1]) i1 = e;
    int i2 = (i1 == 0) ? 1 : 0;
#pragma unroll
    for (int e = 0; e < NEXP; ++e) if (e != i1 && pe[e] > pe[i2]) i2 = e;
    float s2 = pe[i1] + pe[i2];
    tope[t] = i1 | (i2 << 8);
    topw[t * 2 + 0] = pe[i1] / s2;
    topw[t * 2 + 1] = pe[i2] / s2;
  }
}

// ---------------------------------------------------------------------------
// Pyramid cache stage 1: radix select. NEW: bucket-scan parallelized (was a
// tid==0 serial 256-iter LDS dependent chain per level, ~120cyc/iter).
// ---------------------------------------------------------------------------
__global__ __launch_bounds__(256) void cache_select(
    const void* __restrict__ imp, short* __restrict__ listg,
    const int* __restrict__ flag) {
  int isf32 = *flag;
  int e = blockIdx.x, tid = threadIdx.x;
  int n = 2048 - 128 * e, k = n >> 1;
  __shared__ unsigned keys[2048];
  __shared__ int hist[256];
  __shared__ short list[1024];
  __shared__ unsigned s_prefix;
  __shared__ int s_above;
  __shared__ int cnt_gt, cnt_tie;
  for (int i = tid; i < n; i += 256) {
    if (isf32) {
      union { float f; unsigned u; } c; c.f = ((const float*)imp)[e * 2048 + i];
      keys[i] = c.u;
    } else {
      keys[i] = ((unsigned)((const u16*)imp)[e * 2048 + i]) << 16;
    }
  }
  if (tid == 0) { cnt_gt = 0; cnt_tie = 0; }
  __syncthreads();
  unsigned prefix = 0; int above = 0;
  for (int level = 3; level >= 0; --level) {
    hist[tid] = 0;
    __syncthreads();
    for (int i = tid; i < n; i += 256) {
      unsigned kk = keys[i];
      bool m = (level == 3) || ((kk >> ((level + 1) * 8)) == prefix);
      if (m) atomicAdd(&hist[(kk >> (level * 8)) & 255], 1);
    }
    __syncthreads();
    // parallel suffix-count: thread t computes S(t)=sum_{j>=t} hist[j];
    // pick b* = max{b : S(b) >= k-above}  (exactly one thread matches)
    {
      int needl = k - above;
      int S = 0;
      for (int j = tid; j < 256; ++j) S += hist[j];
      int Snext = S - hist[tid];  // = S(tid+1)
      if (S >= needl && (tid == 255 || Snext < needl)) {
        s_above = above + Snext;
        s_prefix = (prefix << 8) | (unsigned)tid;
      }
    }
    __syncthreads();
    prefix = s_prefix; above = s_above;
    __syncthreads();
  }
  int need = k - above;
  for (int i = tid; i < n; i += 256) {
    if (keys[i] > prefix) { int p = atomicAdd(&cnt_gt, 1); list[p] = (short)i; }
  }
  __syncthreads();
  // ties: include the `need` smallest indices with key == pivot.
  for (int i = tid; i < n; i += 256) {
    if (keys[i] == prefix) {
      int r = 0;
      for (int j = 0; j < i; ++j) r += (keys[j] == prefix) ? 1 : 0;
      if (r < need) { int p = atomicAdd(&cnt_tie, 1); list[above + p] = (short)i; }
    }
  }
  __syncthreads();
  for (int i = tid; i < k; i += 256) listg[e * 1024 + i] = list[i];
}

// ---------------------------------------------------------------------------
// Pyramid cache stage 2: mean-pool selected rows over a 32-col slice.
// grid (8, 32) = 256 blocks (was 128) -> 1 block/CU.
// ---------------------------------------------------------------------------
__global__ __launch_bounds__(256) void cache_pool(
    const void* __restrict__ cv, const short* __restrict__ listg,
    float* __restrict__ mean, const int* __restrict__ flag) {
  int isf32 = *flag;
  int e = blockIdx.x, s = blockIdx.y, tid = threadIdx.x;
  int n = 2048 - 128 * e, k = n >> 1;
  int rg = tid >> 3, ct = tid & 7;   // 32 row-groups x 8 col-threads
  int f0 = s * 32 + ct * 4;
  __shared__ short lists[1024];
  __shared__ float red[32][32];
  for (int i = tid; i < k; i += 256) lists[i] = listg[e * 1024 + i];
  __syncthreads();
  float a0 = 0.f, a1 = 0.f, a2 = 0.f, a3 = 0.f;
  if (isf32) {
    const float* cvf = (const float*)cv;
    for (int j = rg; j < k; j += 32) {
      int row = lists[j];
      float4 vv = *(const float4*)(cvf + ((size_t)e * 2048 + row) * HDIM + f0);
      a0 += vv.x; a1 += vv.y; a2 += vv.z; a3 += vv.w;
    }
  } else {
    const u16* cvh = (const u16*)cv;
    for (int j = rg; j < k; j += 32) {
      int row = lists[j];
      uint2 vv = *(const uint2*)(cvh + ((size_t)e * 2048 + row) * HDIM + f0);
      a0 += bf2f((u16)(vv.x & 0xffffu));
      a1 += bf2f((u16)(vv.x >> 16));
      a2 += bf2f((u16)(vv.y & 0xffffu));
      a3 += bf2f((u16)(vv.y >> 16));
    }
  }
  red[rg][ct * 4 + 0] = a0;
  red[rg][ct * 4 + 1] = a1;
  red[rg][ct * 4 + 2] = a2;
  red[rg][ct * 4 + 3] = a3;
  __syncthreads();
  if (tid < 32) {
    float sm = 0.f;
#pragma unroll
    for (int r = 0; r < 32; ++r) sm += red[r][tid];
    mean[(size_t)e * HDIM + s * 32 + tid] = sm / (float)k;
  }
}

// ---------------------------------------------------------------------------
// Pyramid cache stage 3 (unchanged, proven).
// ---------------------------------------------------------------------------
__global__ __launch_bounds__(256) void cache_finalize(
    const float* __restrict__ mean, const void* __restrict__ cla,
    const void* __restrict__ clb, const void* __restrict__ eb,
    float* __restrict__ ec, const int* __restrict__ flag) {
  int isf32 = *flag;
  int e = blockIdx.x, tid = threadIdx.x;
  __shared__ float tmp4[4];
  if (tid < 4) tmp4[tid] = 0.f;
  __syncthreads();
  int f0 = tid * 4;
  float m[4];
#pragma unroll
  for (int i = 0; i < 4; ++i) m[i] = mean[(size_t)e * HDIM + f0 + i];
#pragma unroll
  for (int r = 0; r < 4; ++r) {
    float pr = 0.f;
#pragma unroll
    for (int i = 0; i < 4; ++i)
      pr += m[i] * lde(cla, ((size_t)e * HDIM + f0 + i) * 4 + r, isf32);
    atomicAdd(&tmp4[r], pr);
  }
  __syncthreads();
#pragma unroll
  for (int i = 0; i < 4; ++i) {
    int f = f0 + i;
    float add = 0.f;
#pragma unroll
    for (int r = 0; r < 4; ++r)
      add += tmp4[r] * lde(clb, (size_t)e * 4 * HDIM + r * HDIM + f, isf32);
    ec[e * HDIM + f] = m[i] + LSCALE * add + lde(eb, (size_t)e * HDIM + f, isf32);
  }
}

// ---------------------------------------------------------------------------
// Build per-expert token lists (unchanged, proven).
// ---------------------------------------------------------------------------
__global__ __launch_bounds__(256) void route_build(
    const int* __restrict__ tope, u16* __restrict__ elist, int* __restrict__ ecnt) {
  int e = blockIdx.x;
  __shared__ int c;
  if (threadIdx.x == 0) c = 0;
  __syncthreads();
  for (int t = threadIdx.x; t < NTOK; t += 256) {
    int pe = tope[t];
    int e1 = pe & 255, e2 = (pe >> 8) & 255;
    if (e1 == e) { int p = atomicAdd(&c, 1); elist[e * NTOK + p] = (u16)t; }
    else if (e2 == e) { int p = atomicAdd(&c, 1); elist[e * NTOK + p] = (u16)(t | 0x8000); }
  }
  __syncthreads();
  if (threadIdx.x == 0) ecnt[e] = c;
}

// ---------------------------------------------------------------------------
// Gathered expert GEMM (unchanged, proven).
// ---------------------------------------------------------------------------
__global__ __launch_bounds__(256) void gemm_expert_gather(
    const u16* __restrict__ A, const u16* __restrict__ Bt,
    const float* __restrict__ topw, const u16* __restrict__ elist,
    const int* __restrict__ ecnt, const float* __restrict__ ec,
    float* __restrict__ slot0, float* __restrict__ slot1) {
  const int K = HDIM;
  int mc = blockIdx.x, n0 = blockIdx.y * 128, e = blockIdx.z;
  int cnt = ecnt[e];
  int r0 = mc * 64;
  if (r0 >= cnt) return;
  __shared__ alignas(16) u16 As[64 * 32];
  __shared__ alignas(16) u16 Bs[128 * 32];
  int tid = threadIdx.x, lane = tid & 63, wid = tid >> 6;
  int wm = wid >> 1, wn = wid & 1;
  int q = lane >> 4, lr = lane & 15;
  int srow = wid * 16 + (lane >> 2);
  int scol = (lane & 3) * 8;
  int li = r0 + srow; if (li >= cnt) li = r0;
  int tokme = elist[e * NTOK + li] & 2047;
  const u16* Ag = A + (size_t)tokme * K + scol;
  const u16* Bg = Bt + (size_t)e * K * HDIM + (size_t)(n0 + srow) * K + scol;
  u16* AsL = As + wid * 16 * 32;
  u16* BsL = Bs + wid * 16 * 32;
  f32x4 acc[2][4];
#pragma unroll
  for (int mi = 0; mi < 2; ++mi)
#pragma unroll
    for (int ni = 0; ni < 4; ++ni) acc[mi][ni] = (f32x4){0.f, 0.f, 0.f, 0.f};
  for (int kt = 0; kt < K / 32; ++kt) {
    __syncthreads();
    gload16(Ag + kt * 32, AsL);
    gload16(Bg + kt * 32, BsL);
    gload16(Bg + (size_t)64 * K + kt * 32, BsL + 64 * 32);
    __syncthreads();
    bf16x8 af[2], bfr[4];
#pragma unroll
    for (int mi = 0; mi < 2; ++mi)
      af[mi] = *(const bf16x8*)(As + (wm * 32 + mi * 16 + lr) * 32 + q * 8);
#pragma unroll
    for (int ni = 0; ni < 4; ++ni)
      bfr[ni] = *(const bf16x8*)(Bs + (wn * 64 + ni * 16 + lr) * 32 + q * 8);
#pragma unroll
    for (int mi = 0; mi < 2; ++mi)
#pragma unroll
      for (int ni = 0; ni < 4; ++ni)
        acc[mi][ni] = __builtin_amdgcn_mfma_f32_16x16x32_bf16(af[mi], bfr[ni], acc[mi][ni], 0, 0, 0);
  }
#pragma unroll
  for (int mi = 0; mi < 2; ++mi) {
#pragma unroll
    for (int r = 0; r < 4; ++r) {
      int lrow = wm * 32 + mi * 16 + q * 4 + r;
      int gi = r0 + lrow;
      if (gi >= cnt) continue;
      int ent = elist[e * NTOK + gi];
      int t2 = ent & 2047, sl = ent >> 15;
      float w = topw[t2 * 2 + sl];
      float* dst = sl ? slot1 : slot0;
#pragma unroll
      for (int ni = 0; ni < 4; ++ni) {
        int col = n0 + wn * 64 + ni * 16 + lr;
        dst[(size_t)t2 * HDIM + col] = w * (acc[mi][ni][r] + ec[e * HDIM + col]);
      }
    }
  }
}

// ---------------------------------------------------------------------------
// outh = f2bf(slot0 + slot1) (unchanged, proven).
// ---------------------------------------------------------------------------
__global__ __launch_bounds__(256) void combine_outh(
    const float* __restrict__ s0, const float* __restrict__ s1,
    u16* __restrict__ outh) {
  int i = blockIdx.x * 256 + threadIdx.x;
  float4 a = ((const float4*)s0)[i];
  float4 b = ((const float4*)s1)[i];
  u16 o[4] = { f2bf(a.x + b.x), f2bf(a.y + b.y), f2bf(a.z + b.z), f2bf(a.w + b.w) };
  ((uint2*)outh)[i] = *(uint2*)o;
}

// ---------------------------------------------------------------------------
// Vocab GEMM, 256x256 tile, BK=64, 512 threads (2M x 4N waves, 128x64/wave).
// 8-phase-per-2-K-tiles schedule (T3+T4+T5): per K-tile 4 phases of
// {frag ds_reads | stage 1 K-slab half -> [vmcnt(6) @ p2,p4] -> s_barrier ->
//  lgkmcnt(0) -> setprio(1) -> 16 MFMA -> setprio(0) -> s_barrier}.
// LDS 128KB: [op][buf][kk][256][32] bf16 slabs; dbuf = K-tile parity.
// Stages lead: t+1.k1 at t.p1/p2, t+2.k0 at t.p3/p4 (slab overwrite always
// >=1 barrier after last read; vmcnt(6) leaves exactly newest 3 halves).
// Swizzle: 16B slot phys = logical ^ ((row>>1)&3)  (2-way = free), source
// pre-swizzled per rule 21. Epilogue drains 6 -> 2 -> 0.
// ---------------------------------------------------------------------------
#define VNT 16  // K/64

template<int VM2, int VM4, bool S12, bool S34>
__device__ __forceinline__ void vtile(
    int t, u16* lds, int wid,
    const u16* pA0, const u16* pA1, const u16* pB0, const u16* pB1,
    int aoff, int boff, f32x4 (&acc)[8][4]) {
  int buf = t & 1, obuf = buf ^ 1;
  const u16* As0 = lds + (buf * 2 + 0) * 8192;
  const u16* As1 = lds + (buf * 2 + 1) * 8192;
  const u16* Bs0 = lds + 32768 + (buf * 2 + 0) * 8192;
  const u16* Bs1 = lds + 32768 + (buf * 2 + 1) * 8192;
  bf16x8 af[4], bfr[4];
  // ---- phase 1: kk0, mi 0-3 (+B kk0 frags); stage t+1.A.k1 ----
#pragma unroll
  for (int ni = 0; ni < 4; ++ni) bfr[ni] = *(const bf16x8*)(Bs0 + boff + ni * 512);
#pragma unroll
  for (int j = 0; j < 4; ++j) af[j] = *(const bf16x8*)(As0 + aoff + j * 512);
  if (S12) {
    u16* d = lds + (obuf * 2 + 1) * 8192 + wid * 512;
    gload16(pA0 + (t + 1) * 64 + 32, d);
    gload16(pA1 + (t + 1) * 64 + 32, d + 4096);
  }
  SBAR(); WAITLGKM();
  __builtin_amdgcn_s_setprio(1);
#pragma unroll
  for (int j = 0; j < 4; ++j)
#pragma unroll
    for (int ni = 0; ni < 4; ++ni)
      acc[j][ni] = __builtin_amdgcn_mfma_f32_16x16x32_bf16(af[j], bfr[ni], acc[j][ni], 0, 0, 0);
  __builtin_amdgcn_s_setprio(0);
  SBAR();
  // ---- phase 2: kk0, mi 4-7; stage t+1.B.k1; vmcnt ----
#pragma unroll
  for (int j = 0; j < 4; ++j) af[j] = *(const bf16x8*)(As0 + aoff + (4 + j) * 512);
  if (S12) {
    u16* d = lds + 32768 + (obuf * 2 + 1) * 8192 + wid * 512;
    gload16(pB0 + (t + 1) * 64 + 32, d);
    gload16(pB1 + (t + 1) * 64 + 32, d + 4096);
  }
  waitvm<VM2>();
  SBAR(); WAITLGKM();
  __builtin_amdgcn_s_setprio(1);
#pragma unroll
  for (int j = 0; j < 4; ++j)
#pragma unroll
    for (int ni = 0; ni < 4; ++ni)
      acc[4 + j][ni] = __builtin_amdgcn_mfma_f32_16x16x32_bf16(af[j], bfr[ni], acc[4 + j][ni], 0, 0, 0);
  __builtin_amdgcn_s_setprio(0);
  SBAR();
  // ---- phase 3: kk1, mi 0-3 (+B kk1 frags); stage t+2.A.k0 ----
#pragma unroll
  for (int ni = 0; ni < 4; ++ni) bfr[ni] = *(const bf16x8*)(Bs1 + boff + ni * 512);
#pragma unroll
  for (int j = 0; j < 4; ++j) af[j] = *(const bf16x8*)(As1 + aoff + j * 512);
  if (S34) {
    u16* d = lds + (buf * 2 + 0) * 8192 + wid * 512;
    gload16(pA0 + (t + 2) * 64, d);
    gload16(pA1 + (t + 2) * 64, d + 4096);
  }
  SBAR(); WAITLGKM();
  __builtin_amdgcn_s_setprio(1);
#pragma unroll
  for (int j = 0; j < 4; ++j)
#pragma unroll
    for (int ni = 0; ni < 4; ++ni)
      acc[j][ni] = __builtin_amdgcn_mfma_f32_16x16x32_bf16(af[j], bfr[ni], acc[j][ni], 0, 0, 0);
  __builtin_amdgcn_s_setprio(0);
  SBAR();
  // ---- phase 4: kk1, mi 4-7; stage t+2.B.k0; vmcnt ----
#pragma unroll
  for (int j = 0; j < 4; ++j) af[j] = *(const bf16x8*)(As1 + aoff + (4 + j) * 512);
  if (S34) {
    u16* d = lds + 32768 + (buf * 2 + 0) * 8192 + wid * 512;
    gload16(pB0 + (t + 2) * 64, d);
    gload16(pB1 + (t + 2) * 64, d + 4096);
  }
  waitvm<VM4>();
  SBAR(); WAITLGKM();
  __builtin_amdgcn_s_setprio(1);
#pragma unroll
  for (int j = 0; j < 4; ++j)
#pragma unroll
    for (int ni = 0; ni < 4; ++ni)
      acc[4 + j][ni] = __builtin_amdgcn_mfma_f32_16x16x32_bf16(af[j], bfr[ni], acc[4 + j][ni], 0, 0, 0);
  __builtin_amdgcn_s_setprio(0);
  SBAR();
}

__global__ __launch_bounds__(512) void gemm_vocab(
    const u16* __restrict__ A, const u16* __restrict__ Bt,
    const void* __restrict__ bias, void* __restrict__ outp,
    int n0base, const int* __restrict__ flag) {
  int isf32 = *flag;
  const int K = HDIM, N = VDIM;
  // XCD-chunked bijective swizzle (nwg % 8 == 0), panel-major n.
  int nwg = gridDim.x;
  int per = nwg >> 3;
  int newid = (blockIdx.x & 7) * per + (blockIdx.x >> 3);
  int bn = newid >> 3, bm = newid & 7;
  int m0 = bm * 256, n0l = bn * 256;
  __shared__ alignas(1024) u16 lds[65536];  // 128 KiB
  int tid = threadIdx.x, lane = tid & 63, wid = tid >> 6;
  int wm = wid >> 2, wn = wid & 3;          // 2 x 4 waves
  int q = lane >> 4, lr = lane & 15;
  // fragment-read offsets (u16 units), shared swizzle term
  int colsw = (q ^ ((lr >> 1) & 3)) * 8;
  int aoff = wm * 4096 + lr * 32 + colsw;
  int boff = wn * 2048 + lr * 32 + colsw;
  // staging source pointers: call c covers rows (c*8+wid)*16 .. +15 of the
  // 256-row tile; lane -> local row lane>>2, pre-swizzled 16B slot.
  int srl = lane >> 2;                         // local row 0..15
  int ssw = ((lane & 3) ^ ((srl >> 1) & 3)) * 8;
  const u16* pA0 = A + (size_t)(m0 + wid * 16 + srl) * K + ssw;
  const u16* pA1 = A + (size_t)(m0 + (8 + wid) * 16 + srl) * K + ssw;
  const u16* pB0 = Bt + (size_t)(n0l + wid * 16 + srl) * K + ssw;
  const u16* pB1 = Bt + (size_t)(n0l + (8 + wid) * 16 + srl) * K + ssw;
  f32x4 acc[8][4];
#pragma unroll
  for (int mi = 0; mi < 8; ++mi)
#pragma unroll
    for (int ni = 0; ni < 4; ++ni) acc[mi][ni] = (f32x4){0.f, 0.f, 0.f, 0.f};
  // prologue: t0 {A.k0, B.k0, A.k1, B.k1}, t1 {A.k0, B.k0}; drain to 4.
  {
    u16* dA0 = lds + 0 * 8192 + wid * 512;            // buf0 A kk0
    u16* dB0 = lds + 32768 + 0 * 8192 + wid * 512;    // buf0 B kk0
    u16* dA1 = lds + 1 * 8192 + wid * 512;            // buf0 A kk1
    u16* dB1 = lds + 32768 + 1 * 8192 + wid * 512;    // buf0 B kk1
    u16* eA0 = lds + 2 * 8192 + wid * 512;            // buf1 A kk0
    u16* eB0 = lds + 32768 + 2 * 8192 + wid * 512;    // buf1 B kk0
    gload16(pA0 + 0, dA0);       gload16(pA1 + 0, dA0 + 4096);
    gload16(pB0 + 0, dB0);       gload16(pB1 + 0, dB0 + 4096);
    gload16(pA0 + 32, dA1);      gload16(pA1 + 32, dA1 + 4096);
    gload16(pB0 + 32, dB1);      gload16(pB1 + 32, dB1 + 4096);
    gload16(pA0 + 64, eA0);      gload16(pA1 + 64, eA0 + 4096);
    gload16(pB0 + 64, eB0);      gload16(pB1 + 64, eB0 + 4096);
    asm volatile("s_waitcnt vmcnt(4)" ::: "memory");
    __builtin_amdgcn_sched_barrier(0);
    SBAR();
  }
#pragma unroll 2
  for (int t = 0; t < VNT - 2; ++t)
    vtile<6, 6, true, true>(t, lds, wid, pA0, pA1, pB0, pB1, aoff, boff, acc);
  vtile<6, 2, true, false>(VNT - 2, lds, wid, pA0, pA1, pB0, pB1, aoff, boff, acc);
  vtile<0, 0, false, false>(VNT - 1, lds, wid, pA0, pA1, pB0, pB1, aoff, boff, acc);
  // epilogue
#pragma unroll
  for (int ni = 0; ni < 4; ++ni) {
    int col = n0base + n0l + wn * 64 + ni * 16 + lr;
    float vb = lde(bias, col, isf32);
#pragma unroll
    for (int mi = 0; mi < 8; ++mi) {
#pragma unroll
      for (int r = 0; r < 4; ++r) {
        int row = m0 + wm * 128 + mi * 16 + q * 4 + r;
        float val = acc[mi][ni][r] + vb;
        if (isf32) ((float*)outp)[(size_t)row * N + col] = val;
        else       ((u16*)outp)[(size_t)row * N + col] = f2bf(val);
      }
    }
  }
}

// ---------------------------------------------------------------------------
extern "C" void kernel_launch(void* const* d_in, const int* in_sizes, int n_in,
                              void* d_out, int out_size, void* d_ws, size_t ws_size,
                              hipStream_t stream) {
  const int*  x    = (const int*)d_in[0];
  const void* emb  = d_in[1];
  const void* gw   = d_in[2];
  const void* gb   = d_in[3];
  const void* ew   = d_in[4];
  const void* eb   = d_in[5];
  const void* ela  = d_in[6];
  const void* elb  = d_in[7];
  const void* cv   = d_in[8];
  const void* imp  = d_in[9];
  const void* cla  = d_in[10];
  const void* clb  = d_in[11];
  const void* vw   = d_in[12];
  const void* vb   = d_in[13];

  char* ws = (char*)d_ws;
  u16*   WeffT = (u16*)(ws);                  // 16,777,216 B
  u16*   h_bf  = (u16*)(ws + 16777216);       //  4,194,304 B
  u16*   outh  = (u16*)(ws + 20971520);       //  4,194,304 B
  float* ec    = (float*)(ws + 25165824);     //     32,768 B
  int*   flag  = (int*)(ws + 25198592);       //         64 B
  float* mean  = (float*)(ws + 25198656);     //     32,768 B
  short* listg = (short*)(ws + 25231424);     //     16,384 B
  int*   tope  = (int*)(ws + 25247808);       //      8,192 B
  float* topw  = (float*)(ws + 25256000);     //     16,384 B
  u16*   elist = (u16*)(ws + 25272384);       //     32,768 B
  int*   ecnt  = (int*)(ws + 25305152);       //         64 B
  float* slot0 = (float*)(ws + 25305216);     //  8,388,608 B
  float* slot1 = (float*)(ws + 33693824);     //  8,388,608 B
  u16*   chunk = (u16*)(ws + 42082432);       // vocab WT chunk (<= 64 MB)

  // chunk columns (256-granular); single chunk when ws allows (it does:
  // round-0 FETCH math + 1.049 GB fill => ws ~ 1000 MiB).
  long long avail = (long long)ws_size - 42082432LL;
  long long cc = (avail > 0) ? (avail / (HDIM * 2)) : 0;
  cc &= ~255LL;
  if (cc > VDIM) cc = VDIM;
  if (cc < 256) cc = 256;
  int chunkcols = (int)cc;

  detect_dtype<<<dim3(1), 256, 0, stream>>>((const u16*)emb, flag);
  transpose_lora<<<dim3(HDIM / 64, HDIM / 64, NEXP), 256, 0, stream>>>(
      ew, WeffT, ela, elb, HDIM, HDIM, 1, 0, flag);
  embed_gate<<<dim3(NTOK), 256, 0, stream>>>(x, emb, gw, gb, h_bf, tope, topw, flag);
  cache_select<<<dim3(NEXP), 256, 0, stream>>>(imp, listg, flag);
  cache_pool<<<dim3(NEXP, 32), 256, 0, stream>>>(cv, listg, mean, flag);
  cache_finalize<<<dim3(NEXP), 256, 0, stream>>>(mean, cla, clb, eb, ec, flag);
  route_build<<<dim3(NEXP), 256, 0, stream>>>(tope, elist, ecnt);
  gemm_expert_gather<<<dim3(32, 8, NEXP), 256, 0, stream>>>(
      h_bf, WeffT, topw, elist, ecnt, ec, slot0, slot1);
  combine_outh<<<dim3(NTOK * HDIM / 4 / 256), 256, 0, stream>>>(slot0, slot1, outh);
  for (int c0 = 0; c0 < VDIM; c0 += chunkcols) {
    int nc = (VDIM - c0 < chunkcols) ? (VDIM - c0) : chunkcols;
    transpose_lora<<<dim3(HDIM / 64, nc / 64, 1), 256, 0, stream>>>(
        vw, chunk, nullptr, nullptr, HDIM, VDIM, 0, c0, flag);
    gemm_vocab<<<dim3((nc / 256) * 8), 512, 0, stream>>>(
        outh, chunk, vb, d_out, c0, flag);
  }
}

// Round 10
// 835.025 us; speedup vs baseline: 1.3418x; 1.0063x over previous
//
#include <hip/hip_runtime.h>

typedef unsigned short u16;
typedef __bf16 bf16x8 __attribute__((ext_vector_type(8)));
typedef float f32x4 __attribute__((ext_vector_type(4)));

#define HDIM 1024
#define VDIM 32000
#define NEXP 8
#define NTOK 2048
#define LSCALE 0.25f

__device__ __forceinline__ float bf2f(u16 v) {
  union { unsigned u; float f; } x; x.u = ((unsigned)v) << 16; return x.f;
}
__device__ __forceinline__ u16 f2bf(float f) {
  union { float f; unsigned u; } x; x.f = f;
  return (u16)((x.u + 0x7fffu + ((x.u >> 16) & 1u)) >> 16);
}
__device__ __forceinline__ float lde(const void* p, size_t i, int isf32) {
  if (isf32) return ((const float*)p)[i];
  else       return bf2f(((const u16*)p)[i]);
}

// direct global->LDS async copy, 16B/lane. LDS dest wave-uniform base; HW
// writes base + lane*16. Global source IS per-lane (gather/swizzle legal).
__device__ __forceinline__ void gload16(const u16* g, u16* l) {
  __builtin_amdgcn_global_load_lds(
      (const __attribute__((address_space(1))) void*)g,
      (__attribute__((address_space(3))) void*)l, 16, 0, 0);
}

#define SBAR() do { __builtin_amdgcn_s_barrier(); __builtin_amdgcn_sched_barrier(0); } while (0)
#define WAITLGKM() do { asm volatile("s_waitcnt lgkmcnt(0)" ::: "memory"); __builtin_amdgcn_sched_barrier(0); } while (0)
template<int N> __device__ __forceinline__ void waitvm() {
  if constexpr (N == 8) asm volatile("s_waitcnt vmcnt(8)" ::: "memory");
  else if constexpr (N == 4) asm volatile("s_waitcnt vmcnt(4)" ::: "memory");
  else asm volatile("s_waitcnt vmcnt(0)" ::: "memory");
  __builtin_amdgcn_sched_barrier(0);
}

// ---------------------------------------------------------------------------
// Dtype detector (unchanged, proven).
// ---------------------------------------------------------------------------
__global__ __launch_bounds__(256) void detect_dtype(const u16* __restrict__ emb,
                                                    int* __restrict__ flag) {
  __shared__ int cnt;
  int tid = threadIdx.x;
  if (tid == 0) cnt = 0;
  __syncthreads();
  int sane = 0;
  for (int i = tid; i < 1024; i += 256) {
    u16 v = emb[2 * i];
    int ex = (v >> 7) & 0xff;
    sane += (ex >= 87 && ex <= 127) ? 1 : 0;
  }
  atomicAdd(&cnt, sane);
  __syncthreads();
  if (tid == 0) *flag = (cnt < 512) ? 1 : 0;  // 1 = fp32, 0 = bf16
}

// ---------------------------------------------------------------------------
// Transpose (optionally LoRA-folding) -> bf16 WT. Unchanged, proven.
// ---------------------------------------------------------------------------
__global__ __launch_bounds__(256) void transpose_lora(
    const void* __restrict__ W, u16* __restrict__ WT,
    const void* __restrict__ la, const void* __restrict__ lb,
    int K, int N, int hasLora, int ncol0, const int* __restrict__ flag) {
  int isf32 = *flag;
  int tk = blockIdx.x * 64;
  int tn = ncol0 + blockIdx.y * 64;
  int e  = blockIdx.z;
  __shared__ alignas(16) u16 tile[64][72];
  int tid = threadIdx.x;
  int row = tid >> 2, c0l = (tid & 3) * 16;
  size_t src = (size_t)e * K * N + (size_t)(tk + row) * N + tn + c0l;
  u16 tmp[16];
  if (isf32) {
    const float* Wf = (const float*)W;
#pragma unroll
    for (int j = 0; j < 4; ++j) {
      float4 f = *(const float4*)(Wf + src + j * 4);
      tmp[j * 4 + 0] = f2bf(f.x); tmp[j * 4 + 1] = f2bf(f.y);
      tmp[j * 4 + 2] = f2bf(f.z); tmp[j * 4 + 3] = f2bf(f.w);
    }
  } else {
    const u16* Wh = (const u16*)W;
    *(uint4*)&tmp[0] = *(const uint4*)(Wh + src);
    *(uint4*)&tmp[8] = *(const uint4*)(Wh + src + 8);
  }
  *(uint4*)&tile[row][c0l] = *(uint4*)&tmp[0];
  *(uint4*)&tile[row][c0l + 8] = *(uint4*)&tmp[8];
  __syncthreads();
  int f = tid >> 2;
  int h0 = (tid & 3) * 16;
  float lbv[4];
  if (hasLora) {
#pragma unroll
    for (int r = 0; r < 4; ++r)
      lbv[r] = lde(lb, (size_t)e * 4 * N + (size_t)r * N + tn + f, isf32);
  }
  u16 outv[16];
#pragma unroll
  for (int i = 0; i < 16; ++i) {
    float x = bf2f(tile[h0 + i][f]);
    if (hasLora) {
      size_t lbase = ((size_t)e * K + tk + h0 + i) * 4;
      float s = 0.f;
#pragma unroll
      for (int r = 0; r < 4; ++r) s += lde(la, lbase + r, isf32) * lbv[r];
      x += LSCALE * s;
    }
    outv[i] = f2bf(x);
  }
  u16* dst = WT + (size_t)e * K * N + (size_t)(blockIdx.y * 64 + f) * K + tk + h0;
  *(uint4*)dst = *(uint4*)&outv[0];
  *(uint4*)(dst + 8) = *(uint4*)&outv[8];
}

// ---------------------------------------------------------------------------
// Embedding gather + gate + top-2 routing (unchanged, proven).
// ---------------------------------------------------------------------------
__global__ __launch_bounds__(256) void embed_gate(
    const int* __restrict__ x, const void* __restrict__ emb,
    const void* __restrict__ gw, const void* __restrict__ gb,
    u16* __restrict__ h_bf, int* __restrict__ tope, float* __restrict__ topw,
    const int* __restrict__ flag) {
  int isf32 = *flag;
  int t = blockIdx.x, tid = threadIdx.x;
  __shared__ float hs[HDIM];
  __shared__ float gl[NEXP];
  int idx = x[t];
  if (isf32) {
    const float* er = (const float*)emb + (size_t)idx * HDIM;
    float4 f = ((const float4*)er)[tid];
    u16 h4[4] = { f2bf(f.x), f2bf(f.y), f2bf(f.z), f2bf(f.w) };
    ((uint2*)(h_bf + (size_t)t * HDIM))[tid] = *(uint2*)h4;
    hs[tid * 4 + 0] = f.x; hs[tid * 4 + 1] = f.y;
    hs[tid * 4 + 2] = f.z; hs[tid * 4 + 3] = f.w;
  } else {
    uint2 v = ((const uint2*)((const u16*)emb + (size_t)idx * HDIM))[tid];
    ((uint2*)(h_bf + (size_t)t * HDIM))[tid] = v;
    hs[tid * 4 + 0] = bf2f((u16)(v.x & 0xffffu));
    hs[tid * 4 + 1] = bf2f((u16)(v.x >> 16));
    hs[tid * 4 + 2] = bf2f((u16)(v.y & 0xffffu));
    hs[tid * 4 + 3] = bf2f((u16)(v.y >> 16));
  }
  __syncthreads();
  int wid = tid >> 6, lane = tid & 63;
  int c0 = wid * 2, c1 = c0 + 1;
  float p0 = 0.f, p1 = 0.f;
  for (int i = lane; i < HDIM; i += 64) {
    float hv = hs[i];
    p0 += hv * lde(gw, (size_t)i * 8 + c0, isf32);
    p1 += hv * lde(gw, (size_t)i * 8 + c1, isf32);
  }
#pragma unroll
  for (int off = 32; off; off >>= 1) {
    p0 += __shfl_down(p0, off, 64);
    p1 += __shfl_down(p1, off, 64);
  }
  if (lane == 0) { gl[c0] = p0 + lde(gb, c0, isf32); gl[c1] = p1 + lde(gb, c1, isf32); }
  __syncthreads();
  if (tid == 0) {
    float mx = gl[0];
#pragma unroll
    for (int e = 1; e < NEXP; ++e) mx = fmaxf(mx, gl[e]);
    float pe[NEXP];
#pragma unroll
    for (int e = 0; e < NEXP; ++e) pe[e] = expf(gl[e] - mx);
    int i1 = 0;
#pragma unroll
    for (int e = 1; e < NEXP; ++e) if (pe[e] > pe[i1]) i1 = e;
    int i2 = (i1 == 0) ? 1 : 0;
#pragma unroll
    for (int e = 0; e < NEXP; ++e) if (e != i1 && pe[e] > pe[i2]) i2 = e;
    float s2 = pe[i1] + pe[i2];
    tope[t] = i1 | (i2 << 8);
    topw[t * 2 + 0] = pe[i1] / s2;
    topw[t * 2 + 1] = pe[i2] / s2;
  }
}

// ---------------------------------------------------------------------------
// Pyramid cache stage 1: radix select, parallel bucket-scan + parallel list
// build (unchanged from R4, proven).
// ---------------------------------------------------------------------------
__global__ __launch_bounds__(256) void cache_select(
    const void* __restrict__ imp, short* __restrict__ listg,
    const int* __restrict__ flag) {
  int isf32 = *flag;
  int e = blockIdx.x, tid = threadIdx.x;
  int n = 2048 - 128 * e, k = n >> 1;
  __shared__ unsigned keys[2048];
  __shared__ int hist[256];
  __shared__ short list[1024];
  __shared__ unsigned s_prefix;
  __shared__ int s_above;
  __shared__ int cnt_gt, cnt_tie;
  for (int i = tid; i < n; i += 256) {
    if (isf32) {
      union { float f; unsigned u; } c; c.f = ((const float*)imp)[e * 2048 + i];
      keys[i] = c.u;
    } else {
      keys[i] = ((unsigned)((const u16*)imp)[e * 2048 + i]) << 16;
    }
  }
  if (tid == 0) { cnt_gt = 0; cnt_tie = 0; }
  __syncthreads();
  unsigned prefix = 0; int above = 0;
  for (int level = 3; level >= 0; --level) {
    hist[tid] = 0;
    __syncthreads();
    for (int i = tid; i < n; i += 256) {
      unsigned kk = keys[i];
      bool m = (level == 3) || ((kk >> ((level + 1) * 8)) == prefix);
      if (m) atomicAdd(&hist[(kk >> (level * 8)) & 255], 1);
    }
    __syncthreads();
    {
      int needl = k - above;
      int S = 0;
      for (int j = tid; j < 256; ++j) S += hist[j];
      int Snext = S - hist[tid];
      if (S >= needl && (tid == 255 || Snext < needl)) {
        s_above = above + Snext;
        s_prefix = (prefix << 8) | (unsigned)tid;
      }
    }
    __syncthreads();
    prefix = s_prefix; above = s_above;
    __syncthreads();
  }
  int need = k - above;
  for (int i = tid; i < n; i += 256) {
    if (keys[i] > prefix) { int p = atomicAdd(&cnt_gt, 1); list[p] = (short)i; }
  }
  __syncthreads();
  for (int i = tid; i < n; i += 256) {
    if (keys[i] == prefix) {
      int r = 0;
      for (int j = 0; j < i; ++j) r += (keys[j] == prefix) ? 1 : 0;
      if (r < need) { int p = atomicAdd(&cnt_tie, 1); list[above + p] = (short)i; }
    }
  }
  __syncthreads();
  for (int i = tid; i < k; i += 256) listg[e * 1024 + i] = list[i];
}

// ---------------------------------------------------------------------------
// Pyramid cache stage 2: mean-pool, grid (8,32) (unchanged from R4).
// ---------------------------------------------------------------------------
__global__ __launch_bounds__(256) void cache_pool(
    const void* __restrict__ cv, const short* __restrict__ listg,
    float* __restrict__ mean, const int* __restrict__ flag) {
  int isf32 = *flag;
  int e = blockIdx.x, s = blockIdx.y, tid = threadIdx.x;
  int n = 2048 - 128 * e, k = n >> 1;
  int rg = tid >> 3, ct = tid & 7;
  int f0 = s * 32 + ct * 4;
  __shared__ short lists[1024];
  __shared__ float red[32][32];
  for (int i = tid; i < k; i += 256) lists[i] = listg[e * 1024 + i];
  __syncthreads();
  float a0 = 0.f, a1 = 0.f, a2 = 0.f, a3 = 0.f;
  if (isf32) {
    const float* cvf = (const float*)cv;
    for (int j = rg; j < k; j += 32) {
      int row = lists[j];
      float4 vv = *(const float4*)(cvf + ((size_t)e * 2048 + row) * HDIM + f0);
      a0 += vv.x; a1 += vv.y; a2 += vv.z; a3 += vv.w;
    }
  } else {
    const u16* cvh = (const u16*)cv;
    for (int j = rg; j < k; j += 32) {
      int row = lists[j];
      uint2 vv = *(const uint2*)(cvh + ((size_t)e * 2048 + row) * HDIM + f0);
      a0 += bf2f((u16)(vv.x & 0xffffu));
      a1 += bf2f((u16)(vv.x >> 16));
      a2 += bf2f((u16)(vv.y & 0xffffu));
      a3 += bf2f((u16)(vv.y >> 16));
    }
  }
  red[rg][ct * 4 + 0] = a0;
  red[rg][ct * 4 + 1] = a1;
  red[rg][ct * 4 + 2] = a2;
  red[rg][ct * 4 + 3] = a3;
  __syncthreads();
  if (tid < 32) {
    float sm = 0.f;
#pragma unroll
    for (int r = 0; r < 32; ++r) sm += red[r][tid];
    mean[(size_t)e * HDIM + s * 32 + tid] = sm / (float)k;
  }
}

// ---------------------------------------------------------------------------
// Pyramid cache stage 3 (unchanged, proven).
// ---------------------------------------------------------------------------
__global__ __launch_bounds__(256) void cache_finalize(
    const float* __restrict__ mean, const void* __restrict__ cla,
    const void* __restrict__ clb, const void* __restrict__ eb,
    float* __restrict__ ec, const int* __restrict__ flag) {
  int isf32 = *flag;
  int e = blockIdx.x, tid = threadIdx.x;
  __shared__ float tmp4[4];
  if (tid < 4) tmp4[tid] = 0.f;
  __syncthreads();
  int f0 = tid * 4;
  float m[4];
#pragma unroll
  for (int i = 0; i < 4; ++i) m[i] = mean[(size_t)e * HDIM + f0 + i];
#pragma unroll
  for (int r = 0; r < 4; ++r) {
    float pr = 0.f;
#pragma unroll
    for (int i = 0; i < 4; ++i)
      pr += m[i] * lde(cla, ((size_t)e * HDIM + f0 + i) * 4 + r, isf32);
    atomicAdd(&tmp4[r], pr);
  }
  __syncthreads();
#pragma unroll
  for (int i = 0; i < 4; ++i) {
    int f = f0 + i;
    float add = 0.f;
#pragma unroll
    for (int r = 0; r < 4; ++r)
      add += tmp4[r] * lde(clb, (size_t)e * 4 * HDIM + r * HDIM + f, isf32);
    ec[e * HDIM + f] = m[i] + LSCALE * add + lde(eb, (size_t)e * HDIM + f, isf32);
  }
}

// ---------------------------------------------------------------------------
// Build per-expert token lists (unchanged, proven).
// ---------------------------------------------------------------------------
__global__ __launch_bounds__(256) void route_build(
    const int* __restrict__ tope, u16* __restrict__ elist, int* __restrict__ ecnt) {
  int e = blockIdx.x;
  __shared__ int c;
  if (threadIdx.x == 0) c = 0;
  __syncthreads();
  for (int t = threadIdx.x; t < NTOK; t += 256) {
    int pe = tope[t];
    int e1 = pe & 255, e2 = (pe >> 8) & 255;
    if (e1 == e) { int p = atomicAdd(&c, 1); elist[e * NTOK + p] = (u16)t; }
    else if (e2 == e) { int p = atomicAdd(&c, 1); elist[e * NTOK + p] = (u16)(t | 0x8000); }
  }
  __syncthreads();
  if (threadIdx.x == 0) ecnt[e] = c;
}

// ---------------------------------------------------------------------------
// Gathered expert GEMM (unchanged, proven).
// ---------------------------------------------------------------------------
__global__ __launch_bounds__(256) void gemm_expert_gather(
    const u16* __restrict__ A, const u16* __restrict__ Bt,
    const float* __restrict__ topw, const u16* __restrict__ elist,
    const int* __restrict__ ecnt, const float* __restrict__ ec,
    float* __restrict__ slot0, float* __restrict__ slot1) {
  const int K = HDIM;
  int mc = blockIdx.x, n0 = blockIdx.y * 128, e = blockIdx.z;
  int cnt = ecnt[e];
  int r0 = mc * 64;
  if (r0 >= cnt) return;
  __shared__ alignas(16) u16 As[64 * 32];
  __shared__ alignas(16) u16 Bs[128 * 32];
  int tid = threadIdx.x, lane = tid & 63, wid = tid >> 6;
  int wm = wid >> 1, wn = wid & 1;
  int q = lane >> 4, lr = lane & 15;
  int srow = wid * 16 + (lane >> 2);
  int scol = (lane & 3) * 8;
  int li = r0 + srow; if (li >= cnt) li = r0;
  int tokme = elist[e * NTOK + li] & 2047;
  const u16* Ag = A + (size_t)tokme * K + scol;
  const u16* Bg = Bt + (size_t)e * K * HDIM + (size_t)(n0 + srow) * K + scol;
  u16* AsL = As + wid * 16 * 32;
  u16* BsL = Bs + wid * 16 * 32;
  f32x4 acc[2][4];
#pragma unroll
  for (int mi = 0; mi < 2; ++mi)
#pragma unroll
    for (int ni = 0; ni < 4; ++ni) acc[mi][ni] = (f32x4){0.f, 0.f, 0.f, 0.f};
  for (int kt = 0; kt < K / 32; ++kt) {
    __syncthreads();
    gload16(Ag + kt * 32, AsL);
    gload16(Bg + kt * 32, BsL);
    gload16(Bg + (size_t)64 * K + kt * 32, BsL + 64 * 32);
    __syncthreads();
    bf16x8 af[2], bfr[4];
#pragma unroll
    for (int mi = 0; mi < 2; ++mi)
      af[mi] = *(const bf16x8*)(As + (wm * 32 + mi * 16 + lr) * 32 + q * 8);
#pragma unroll
    for (int ni = 0; ni < 4; ++ni)
      bfr[ni] = *(const bf16x8*)(Bs + (wn * 64 + ni * 16 + lr) * 32 + q * 8);
#pragma unroll
    for (int mi = 0; mi < 2; ++mi)
#pragma unroll
      for (int ni = 0; ni < 4; ++ni)
        acc[mi][ni] = __builtin_amdgcn_mfma_f32_16x16x32_bf16(af[mi], bfr[ni], acc[mi][ni], 0, 0, 0);
  }
#pragma unroll
  for (int mi = 0; mi < 2; ++mi) {
#pragma unroll
    for (int r = 0; r < 4; ++r) {
      int lrow = wm * 32 + mi * 16 + q * 4 + r;
      int gi = r0 + lrow;
      if (gi >= cnt) continue;
      int ent = elist[e * NTOK + gi];
      int t2 = ent & 2047, sl = ent >> 15;
      float w = topw[t2 * 2 + sl];
      float* dst = sl ? slot1 : slot0;
#pragma unroll
      for (int ni = 0; ni < 4; ++ni) {
        int col = n0 + wn * 64 + ni * 16 + lr;
        dst[(size_t)t2 * HDIM + col] = w * (acc[mi][ni][r] + ec[e * HDIM + col]);
      }
    }
  }
}

// ---------------------------------------------------------------------------
// outh = f2bf(slot0 + slot1) (unchanged, proven).
// ---------------------------------------------------------------------------
__global__ __launch_bounds__(256) void combine_outh(
    const float* __restrict__ s0, const float* __restrict__ s1,
    u16* __restrict__ outh) {
  int i = blockIdx.x * 256 + threadIdx.x;
  float4 a = ((const float4*)s0)[i];
  float4 b = ((const float4*)s1)[i];
  u16 o[4] = { f2bf(a.x + b.x), f2bf(a.y + b.y), f2bf(a.z + b.z), f2bf(a.w + b.w) };
  ((uint2*)outh)[i] = *(uint2*)o;
}

// ---------------------------------------------------------------------------
// Vocab GEMM, 256x256 tile, BK=64, 512 threads (2M x 4N waves, 128x64/wave).
// SINGLE-BARRIER phases (R4 post-mortem: two barriers/phase lockstep-
// serialized the LDS-read pipe (768cyc/CU/phase) against the MFMA pipe
// (620cyc) -> 1920cyc phases, MfmaUtil 29%). Per phase now:
//   [stage issue][frag ds_reads][lgkmcnt(0)][MFMA][vmcnt(8) @p2,p4][s_barrier]
// Hazard audit (r5, r6 per-wave vmcnt issue-trace, r8 hang audit):
// read-before-overwrite holds because each phase's ds_reads drain (lgkm0)
// before its end-barrier and re-staging issues after a later barrier
// (As0 r:p1,p2 w:p3 | As1 r:p3,p4 w:p1' | Bs0 r:p1 w:p4 | Bs1 r:p3 w:p2').
// Staging-complete: per-wave issue trace shows each vmcnt(8) drains exactly
// the slab pair read two phases later (prologue: 12 issued, vmcnt(4) leaves
// buf1 quad; steady: +8/tile, two vmcnt(8) waits). Tail: vmcnt(4)@t14.P4,
// vmcnt(0)@t15. No divergent barrier counts; all staged addrs in-bounds.
// ---------------------------------------------------------------------------
#define VNT 16  // K/64

template<int VM2, int VM4, bool S12, bool S34>
__device__ __forceinline__ void vtile(
    int t, u16* lds, int wid,
    const u16* pA0, const u16* pA1, const u16* pB0, const u16* pB1,
    int aoff, int boff, f32x4 (&acc)[8][4]) {
  int buf = t & 1, obuf = buf ^ 1;
  const u16* As0 = lds + (buf * 2 + 0) * 8192;
  const u16* As1 = lds + (buf * 2 + 1) * 8192;
  const u16* Bs0 = lds + 32768 + (buf * 2 + 0) * 8192;
  const u16* Bs1 = lds + 32768 + (buf * 2 + 1) * 8192;
  bf16x8 af[4], bfr[4];
  // ---- phase 1: stage t+1.A.k1; read kk0 frags (B + A mi0-3); MFMA ----
  if (S12) {
    u16* d = lds + (obuf * 2 + 1) * 8192 + wid * 512;
    gload16(pA0 + (t + 1) * 64 + 32, d);
    gload16(pA1 + (t + 1) * 64 + 32, d + 4096);
  }
#pragma unroll
  for (int ni = 0; ni < 4; ++ni) bfr[ni] = *(const bf16x8*)(Bs0 + boff + ni * 512);
#pragma unroll
  for (int j = 0; j < 4; ++j) af[j] = *(const bf16x8*)(As0 + aoff + j * 512);
  WAITLGKM();
  __builtin_amdgcn_s_setprio(1);
#pragma unroll
  for (int j = 0; j < 4; ++j)
#pragma unroll
    for (int ni = 0; ni < 4; ++ni)
      acc[j][ni] = __builtin_amdgcn_mfma_f32_16x16x32_bf16(af[j], bfr[ni], acc[j][ni], 0, 0, 0);
  __builtin_amdgcn_s_setprio(0);
  SBAR();
  // ---- phase 2: stage t+1.B.k1; read A kk0 mi4-7; MFMA; vmcnt; bar ----
  if (S12) {
    u16* d = lds + 32768 + (obuf * 2 + 1) * 8192 + wid * 512;
    gload16(pB0 + (t + 1) * 64 + 32, d);
    gload16(pB1 + (t + 1) * 64 + 32, d + 4096);
  }
#pragma unroll
  for (int j = 0; j < 4; ++j) af[j] = *(const bf16x8*)(As0 + aoff + (4 + j) * 512);
  WAITLGKM();
  __builtin_amdgcn_s_setprio(1);
#pragma unroll
  for (int j = 0; j < 4; ++j)
#pragma unroll
    for (int ni = 0; ni < 4; ++ni)
      acc[4 + j][ni] = __builtin_amdgcn_mfma_f32_16x16x32_bf16(af[j], bfr[ni], acc[4 + j][ni], 0, 0, 0);
  __builtin_amdgcn_s_setprio(0);
  waitvm<VM2>();
  SBAR();
  // ---- phase 3: stage t+2.A.k0; read kk1 frags (B + A mi0-3); MFMA ----
  if (S34) {
    u16* d = lds + (buf * 2 + 0) * 8192 + wid * 512;
    gload16(pA0 + (t + 2) * 64, d);
    gload16(pA1 + (t + 2) * 64, d + 4096);
  }
#pragma unroll
  for (int ni = 0; ni < 4; ++ni) bfr[ni] = *(const bf16x8*)(Bs1 + boff + ni * 512);
#pragma unroll
  for (int j = 0; j < 4; ++j) af[j] = *(const bf16x8*)(As1 + aoff + j * 512);
  WAITLGKM();
  __builtin_amdgcn_s_setprio(1);
#pragma unroll
  for (int j = 0; j < 4; ++j)
#pragma unroll
    for (int ni = 0; ni < 4; ++ni)
      acc[j][ni] = __builtin_amdgcn_mfma_f32_16x16x32_bf16(af[j], bfr[ni], acc[j][ni], 0, 0, 0);
  __builtin_amdgcn_s_setprio(0);
  SBAR();
  // ---- phase 4: stage t+2.B.k0; read A kk1 mi4-7; MFMA; vmcnt; bar ----
  if (S34) {
    u16* d = lds + 32768 + (buf * 2 + 0) * 8192 + wid * 512;
    gload16(pB0 + (t + 2) * 64, d);
    gload16(pB1 + (t + 2) * 64, d + 4096);
  }
#pragma unroll
  for (int j = 0; j < 4; ++j) af[j] = *(const bf16x8*)(As1 + aoff + (4 + j) * 512);
  WAITLGKM();
  __builtin_amdgcn_s_setprio(1);
#pragma unroll
  for (int j = 0; j < 4; ++j)
#pragma unroll
    for (int ni = 0; ni < 4; ++ni)
      acc[4 + j][ni] = __builtin_amdgcn_mfma_f32_16x16x32_bf16(af[j], bfr[ni], acc[4 + j][ni], 0, 0, 0);
  __builtin_amdgcn_s_setprio(0);
  waitvm<VM4>();
  SBAR();
}

__global__ __launch_bounds__(512) void gemm_vocab(
    const u16* __restrict__ A, const u16* __restrict__ Bt,
    const void* __restrict__ bias, void* __restrict__ outp,
    int n0base, const int* __restrict__ flag) {
  int isf32 = *flag;
  const int K = HDIM, N = VDIM;
  int nwg = gridDim.x;
  int per = nwg >> 3;
  int newid = (blockIdx.x & 7) * per + (blockIdx.x >> 3);
  int bn = newid >> 3, bm = newid & 7;
  int m0 = bm * 256, n0l = bn * 256;
  __shared__ alignas(1024) u16 lds[65536];  // 128 KiB
  int tid = threadIdx.x, lane = tid & 63, wid = tid >> 6;
  int wm = wid >> 2, wn = wid & 3;
  int q = lane >> 4, lr = lane & 15;
  int colsw = (q ^ ((lr >> 1) & 3)) * 8;
  int aoff = wm * 4096 + lr * 32 + colsw;
  int boff = wn * 2048 + lr * 32 + colsw;
  int srl = lane >> 2;
  int ssw = ((lane & 3) ^ ((srl >> 1) & 3)) * 8;
  const u16* pA0 = A + (size_t)(m0 + wid * 16 + srl) * K + ssw;
  const u16* pA1 = A + (size_t)(m0 + (8 + wid) * 16 + srl) * K + ssw;
  const u16* pB0 = Bt + (size_t)(n0l + wid * 16 + srl) * K + ssw;
  const u16* pB1 = Bt + (size_t)(n0l + (8 + wid) * 16 + srl) * K + ssw;
  f32x4 acc[8][4];
#pragma unroll
  for (int mi = 0; mi < 8; ++mi)
#pragma unroll
    for (int ni = 0; ni < 4; ++ni) acc[mi][ni] = (f32x4){0.f, 0.f, 0.f, 0.f};
  {
    u16* dA0 = lds + 0 * 8192 + wid * 512;
    u16* dB0 = lds + 32768 + 0 * 8192 + wid * 512;
    u16* dA1 = lds + 1 * 8192 + wid * 512;
    u16* dB1 = lds + 32768 + 1 * 8192 + wid * 512;
    u16* eA0 = lds + 2 * 8192 + wid * 512;
    u16* eB0 = lds + 32768 + 2 * 8192 + wid * 512;
    gload16(pA0 + 0, dA0);       gload16(pA1 + 0, dA0 + 4096);
    gload16(pB0 + 0, dB0);       gload16(pB1 + 0, dB0 + 4096);
    gload16(pA0 + 32, dA1);      gload16(pA1 + 32, dA1 + 4096);
    gload16(pB0 + 32, dB1);      gload16(pB1 + 32, dB1 + 4096);
    gload16(pA0 + 64, eA0);      gload16(pA1 + 64, eA0 + 4096);
    gload16(pB0 + 64, eB0);      gload16(pB1 + 64, eB0 + 4096);
    asm volatile("s_waitcnt vmcnt(4)" ::: "memory");
    __builtin_amdgcn_sched_barrier(0);
    SBAR();
  }
#pragma unroll 2
  for (int t = 0; t < VNT - 2; ++t)
    vtile<8, 8, true, true>(t, lds, wid, pA0, pA1, pB0, pB1, aoff, boff, acc);
  vtile<8, 4, true, false>(VNT - 2, lds, wid, pA0, pA1, pB0, pB1, aoff, boff, acc);
  vtile<0, 0, false, false>(VNT - 1, lds, wid, pA0, pA1, pB0, pB1, aoff, boff, acc);
#pragma unroll
  for (int ni = 0; ni < 4; ++ni) {
    int col = n0base + n0l + wn * 64 + ni * 16 + lr;
    float vb = lde(bias, col, isf32);
#pragma unroll
    for (int mi = 0; mi < 8; ++mi) {
#pragma unroll
      for (int r = 0; r < 4; ++r) {
        int row = m0 + wm * 128 + mi * 16 + q * 4 + r;
        float val = acc[mi][ni][r] + vb;
        if (isf32) ((float*)outp)[(size_t)row * N + col] = val;
        else       ((u16*)outp)[(size_t)row * N + col] = f2bf(val);
      }
    }
  }
}

// ---------------------------------------------------------------------------
extern "C" void kernel_launch(void* const* d_in, const int* in_sizes, int n_in,
                              void* d_out, int out_size, void* d_ws, size_t ws_size,
                              hipStream_t stream) {
  const int*  x    = (const int*)d_in[0];
  const void* emb  = d_in[1];
  const void* gw   = d_in[2];
  const void* gb   = d_in[3];
  const void* ew   = d_in[4];
  const void* eb   = d_in[5];
  const void* ela  = d_in[6];
  const void* elb  = d_in[7];
  const void* cv   = d_in[8];
  const void* imp  = d_in[9];
  const void* cla  = d_in[10];
  const void* clb  = d_in[11];
  const void* vw   = d_in[12];
  const void* vb   = d_in[13];

  char* ws = (char*)d_ws;
  u16*   WeffT = (u16*)(ws);                  // 16,777,216 B
  u16*   h_bf  = (u16*)(ws + 16777216);       //  4,194,304 B
  u16*   outh  = (u16*)(ws + 20971520);       //  4,194,304 B
  float* ec    = (float*)(ws + 25165824);     //     32,768 B
  int*   flag  = (int*)(ws + 25198592);       //         64 B
  float* mean  = (float*)(ws + 25198656);     //     32,768 B
  short* listg = (short*)(ws + 25231424);     //     16,384 B
  int*   tope  = (int*)(ws + 25247808);       //      8,192 B
  float* topw  = (float*)(ws + 25256000);     //     16,384 B
  u16*   elist = (u16*)(ws + 25272384);       //     32,768 B
  int*   ecnt  = (int*)(ws + 25305152);       //         64 B
  float* slot0 = (float*)(ws + 25305216);     //  8,388,608 B
  float* slot1 = (float*)(ws + 33693824);     //  8,388,608 B
  u16*   chunk = (u16*)(ws + 42082432);       // vocab WT chunk (<= 64 MB)

  long long avail = (long long)ws_size - 42082432LL;
  long long cc = (avail > 0) ? (avail / (HDIM * 2)) : 0;
  cc &= ~255LL;
  if (cc > VDIM) cc = VDIM;
  if (cc < 256) cc = 256;
  int chunkcols = (int)cc;

  detect_dtype<<<dim3(1), 256, 0, stream>>>((const u16*)emb, flag);
  transpose_lora<<<dim3(HDIM / 64, HDIM / 64, NEXP), 256, 0, stream>>>(
      ew, WeffT, ela, elb, HDIM, HDIM, 1, 0, flag);
  embed_gate<<<dim3(NTOK), 256, 0, stream>>>(x, emb, gw, gb, h_bf, tope, topw, flag);
  cache_select<<<dim3(NEXP), 256, 0, stream>>>(imp, listg, flag);
  cache_pool<<<dim3(NEXP, 32), 256, 0, stream>>>(cv, listg, mean, flag);
  cache_finalize<<<dim3(NEXP), 256, 0, stream>>>(mean, cla, clb, eb, ec, flag);
  route_build<<<dim3(NEXP), 256, 0, stream>>>(tope, elist, ecnt);
  gemm_expert_gather<<<dim3(32, 8, NEXP), 256, 0, stream>>>(
      h_bf, WeffT, topw, elist, ecnt, ec, slot0, slot1);
  combine_outh<<<dim3(NTOK * HDIM / 4 / 256), 256, 0, stream>>>(slot0, slot1, outh);
  for (int c0 = 0; c0 < VDIM; c0 += chunkcols) {
    int nc = (VDIM - c0 < chunkcols) ? (VDIM - c0) : chunkcols;
    transpose_lora<<<dim3(HDIM / 64, nc / 64, 1), 256, 0, stream>>>(
        vw, chunk, nullptr, nullptr, HDIM, VDIM, 0, c0, flag);
    gemm_vocab<<<dim3((nc / 256) * 8), 512, 0, stream>>>(
        outh, chunk, vb, d_out, c0, flag);
  }
}

// Round 13
// 834.446 us; speedup vs baseline: 1.3427x; 1.0007x over previous
//
#include <hip/hip_runtime.h>

typedef unsigned short u16;
typedef __bf16 bf16x8 __attribute__((ext_vector_type(8)));
typedef float f32x4 __attribute__((ext_vector_type(4)));

#define HDIM 1024
#define VDIM 32000
#define NEXP 8
#define NTOK 2048
#define LSCALE 0.25f

__device__ __forceinline__ float bf2f(u16 v) {
  union { unsigned u; float f; } x; x.u = ((unsigned)v) << 16; return x.f;
}
__device__ __forceinline__ u16 f2bf(float f) {
  union { float f; unsigned u; } x; x.f = f;
  return (u16)((x.u + 0x7fffu + ((x.u >> 16) & 1u)) >> 16);
}
__device__ __forceinline__ float lde(const void* p, size_t i, int isf32) {
  if (isf32) return ((const float*)p)[i];
  else       return bf2f(((const u16*)p)[i]);
}

// direct global->LDS async copy, 16B/lane. LDS dest wave-uniform base; HW
// writes base + lane*16. Global source IS per-lane (gather/swizzle legal).
__device__ __forceinline__ void gload16(const u16* g, u16* l) {
  __builtin_amdgcn_global_load_lds(
      (const __attribute__((address_space(1))) void*)g,
      (__attribute__((address_space(3))) void*)l, 16, 0, 0);
}

// Barrier with scheduling walls on BOTH sides: ds_reads may not hoist above
// (slab not yet staged) and MFMA+waits may not sink below (slab about to be
// overwritten). WITHIN a phase the compiler is now free to interleave
// ds_reads and MFMAs with fine-grained lgkmcnt (R10 post-mortem: the
// explicit lgkmcnt(0)+sched_barrier walls per phase were the m141-style
// over-pinning — R4 (2 bar/phase) == R10 (1 bar/phase) == 672 TF).
#define SBAR() do { __builtin_amdgcn_sched_barrier(0); __builtin_amdgcn_s_barrier(); __builtin_amdgcn_sched_barrier(0); } while (0)
template<int N> __device__ __forceinline__ void waitvm() {
  if constexpr (N == 8) asm volatile("s_waitcnt vmcnt(8)" ::: "memory");
  else if constexpr (N == 4) asm volatile("s_waitcnt vmcnt(4)" ::: "memory");
  else asm volatile("s_waitcnt vmcnt(0)" ::: "memory");
}

// ---------------------------------------------------------------------------
// Dtype detector (unchanged, proven).
// ---------------------------------------------------------------------------
__global__ __launch_bounds__(256) void detect_dtype(const u16* __restrict__ emb,
                                                    int* __restrict__ flag) {
  __shared__ int cnt;
  int tid = threadIdx.x;
  if (tid == 0) cnt = 0;
  __syncthreads();
  int sane = 0;
  for (int i = tid; i < 1024; i += 256) {
    u16 v = emb[2 * i];
    int ex = (v >> 7) & 0xff;
    sane += (ex >= 87 && ex <= 127) ? 1 : 0;
  }
  atomicAdd(&cnt, sane);
  __syncthreads();
  if (tid == 0) *flag = (cnt < 512) ? 1 : 0;  // 1 = fp32, 0 = bf16
}

// ---------------------------------------------------------------------------
// Transpose (optionally LoRA-folding) -> bf16 WT. Unchanged, proven.
// ---------------------------------------------------------------------------
__global__ __launch_bounds__(256) void transpose_lora(
    const void* __restrict__ W, u16* __restrict__ WT,
    const void* __restrict__ la, const void* __restrict__ lb,
    int K, int N, int hasLora, int ncol0, const int* __restrict__ flag) {
  int isf32 = *flag;
  int tk = blockIdx.x * 64;
  int tn = ncol0 + blockIdx.y * 64;
  int e  = blockIdx.z;
  __shared__ alignas(16) u16 tile[64][72];
  int tid = threadIdx.x;
  int row = tid >> 2, c0l = (tid & 3) * 16;
  size_t src = (size_t)e * K * N + (size_t)(tk + row) * N + tn + c0l;
  u16 tmp[16];
  if (isf32) {
    const float* Wf = (const float*)W;
#pragma unroll
    for (int j = 0; j < 4; ++j) {
      float4 f = *(const float4*)(Wf + src + j * 4);
      tmp[j * 4 + 0] = f2bf(f.x); tmp[j * 4 + 1] = f2bf(f.y);
      tmp[j * 4 + 2] = f2bf(f.z); tmp[j * 4 + 3] = f2bf(f.w);
    }
  } else {
    const u16* Wh = (const u16*)W;
    *(uint4*)&tmp[0] = *(const uint4*)(Wh + src);
    *(uint4*)&tmp[8] = *(const uint4*)(Wh + src + 8);
  }
  *(uint4*)&tile[row][c0l] = *(uint4*)&tmp[0];
  *(uint4*)&tile[row][c0l + 8] = *(uint4*)&tmp[8];
  __syncthreads();
  int f = tid >> 2;
  int h0 = (tid & 3) * 16;
  float lbv[4];
  if (hasLora) {
#pragma unroll
    for (int r = 0; r < 4; ++r)
      lbv[r] = lde(lb, (size_t)e * 4 * N + (size_t)r * N + tn + f, isf32);
  }
  u16 outv[16];
#pragma unroll
  for (int i = 0; i < 16; ++i) {
    float x = bf2f(tile[h0 + i][f]);
    if (hasLora) {
      size_t lbase = ((size_t)e * K + tk + h0 + i) * 4;
      float s = 0.f;
#pragma unroll
      for (int r = 0; r < 4; ++r) s += lde(la, lbase + r, isf32) * lbv[r];
      x += LSCALE * s;
    }
    outv[i] = f2bf(x);
  }
  u16* dst = WT + (size_t)e * K * N + (size_t)(blockIdx.y * 64 + f) * K + tk + h0;
  *(uint4*)dst = *(uint4*)&outv[0];
  *(uint4*)(dst + 8) = *(uint4*)&outv[8];
}

// ---------------------------------------------------------------------------
// Embedding gather + gate + top-2 routing (unchanged, proven).
// ---------------------------------------------------------------------------
__global__ __launch_bounds__(256) void embed_gate(
    const int* __restrict__ x, const void* __restrict__ emb,
    const void* __restrict__ gw, const void* __restrict__ gb,
    u16* __restrict__ h_bf, int* __restrict__ tope, float* __restrict__ topw,
    const int* __restrict__ flag) {
  int isf32 = *flag;
  int t = blockIdx.x, tid = threadIdx.x;
  __shared__ float hs[HDIM];
  __shared__ float gl[NEXP];
  int idx = x[t];
  if (isf32) {
    const float* er = (const float*)emb + (size_t)idx * HDIM;
    float4 f = ((const float4*)er)[tid];
    u16 h4[4] = { f2bf(f.x), f2bf(f.y), f2bf(f.z), f2bf(f.w) };
    ((uint2*)(h_bf + (size_t)t * HDIM))[tid] = *(uint2*)h4;
    hs[tid * 4 + 0] = f.x; hs[tid * 4 + 1] = f.y;
    hs[tid * 4 + 2] = f.z; hs[tid * 4 + 3] = f.w;
  } else {
    uint2 v = ((const uint2*)((const u16*)emb + (size_t)idx * HDIM))[tid];
    ((uint2*)(h_bf + (size_t)t * HDIM))[tid] = v;
    hs[tid * 4 + 0] = bf2f((u16)(v.x & 0xffffu));
    hs[tid * 4 + 1] = bf2f((u16)(v.x >> 16));
    hs[tid * 4 + 2] = bf2f((u16)(v.y & 0xffffu));
    hs[tid * 4 + 3] = bf2f((u16)(v.y >> 16));
  }
  __syncthreads();
  int wid = tid >> 6, lane = tid & 63;
  int c0 = wid * 2, c1 = c0 + 1;
  float p0 = 0.f, p1 = 0.f;
  for (int i = lane; i < HDIM; i += 64) {
    float hv = hs[i];
    p0 += hv * lde(gw, (size_t)i * 8 + c0, isf32);
    p1 += hv * lde(gw, (size_t)i * 8 + c1, isf32);
  }
#pragma unroll
  for (int off = 32; off; off >>= 1) {
    p0 += __shfl_down(p0, off, 64);
    p1 += __shfl_down(p1, off, 64);
  }
  if (lane == 0) { gl[c0] = p0 + lde(gb, c0, isf32); gl[c1] = p1 + lde(gb, c1, isf32); }
  __syncthreads();
  if (tid == 0) {
    float mx = gl[0];
#pragma unroll
    for (int e = 1; e < NEXP; ++e) mx = fmaxf(mx, gl[e]);
    float pe[NEXP];
#pragma unroll
    for (int e = 0; e < NEXP; ++e) pe[e] = expf(gl[e] - mx);
    int i1 = 0;
#pragma unroll
    for (int e = 1; e < NEXP; ++e) if (pe[e] > pe[i1]) i1 = e;
    int i2 = (i1 == 0) ? 1 : 0;
#pragma unroll
    for (int e = 0; e < NEXP; ++e) if (e != i1 && pe[e] > pe[i2]) i2 = e;
    float s2 = pe[i1] + pe[i2];
    tope[t] = i1 | (i2 << 8);
    topw[t * 2 + 0] = pe[i1] / s2;
    topw[t * 2 + 1] = pe[i2] / s2;
  }
}

// ---------------------------------------------------------------------------
// Pyramid cache stage 1: radix select, parallel bucket-scan + parallel list
// build (unchanged from R4, proven).
// ---------------------------------------------------------------------------
__global__ __launch_bounds__(256) void cache_select(
    const void* __restrict__ imp, short* __restrict__ listg,
    const int* __restrict__ flag) {
  int isf32 = *flag;
  int e = blockIdx.x, tid = threadIdx.x;
  int n = 2048 - 128 * e, k = n >> 1;
  __shared__ unsigned keys[2048];
  __shared__ int hist[256];
  __shared__ short list[1024];
  __shared__ unsigned s_prefix;
  __shared__ int s_above;
  __shared__ int cnt_gt, cnt_tie;
  for (int i = tid; i < n; i += 256) {
    if (isf32) {
      union { float f; unsigned u; } c; c.f = ((const float*)imp)[e * 2048 + i];
      keys[i] = c.u;
    } else {
      keys[i] = ((unsigned)((const u16*)imp)[e * 2048 + i]) << 16;
    }
  }
  if (tid == 0) { cnt_gt = 0; cnt_tie = 0; }
  __syncthreads();
  unsigned prefix = 0; int above = 0;
  for (int level = 3; level >= 0; --level) {
    hist[tid] = 0;
    __syncthreads();
    for (int i = tid; i < n; i += 256) {
      unsigned kk = keys[i];
      bool m = (level == 3) || ((kk >> ((level + 1) * 8)) == prefix);
      if (m) atomicAdd(&hist[(kk >> (level * 8)) & 255], 1);
    }
    __syncthreads();
    {
      int needl = k - above;
      int S = 0;
      for (int j = tid; j < 256; ++j) S += hist[j];
      int Snext = S - hist[tid];
      if (S >= needl && (tid == 255 || Snext < needl)) {
        s_above = above + Snext;
        s_prefix = (prefix << 8) | (unsigned)tid;
      }
    }
    __syncthreads();
    prefix = s_prefix; above = s_above;
    __syncthreads();
  }
  int need = k - above;
  for (int i = tid; i < n; i += 256) {
    if (keys[i] > prefix) { int p = atomicAdd(&cnt_gt, 1); list[p] = (short)i; }
  }
  __syncthreads();
  for (int i = tid; i < n; i += 256) {
    if (keys[i] == prefix) {
      int r = 0;
      for (int j = 0; j < i; ++j) r += (keys[j] == prefix) ? 1 : 0;
      if (r < need) { int p = atomicAdd(&cnt_tie, 1); list[above + p] = (short)i; }
    }
  }
  __syncthreads();
  for (int i = tid; i < k; i += 256) listg[e * 1024 + i] = list[i];
}

// ---------------------------------------------------------------------------
// Pyramid cache stage 2: mean-pool, grid (8,32) (unchanged from R4).
// ---------------------------------------------------------------------------
__global__ __launch_bounds__(256) void cache_pool(
    const void* __restrict__ cv, const short* __restrict__ listg,
    float* __restrict__ mean, const int* __restrict__ flag) {
  int isf32 = *flag;
  int e = blockIdx.x, s = blockIdx.y, tid = threadIdx.x;
  int n = 2048 - 128 * e, k = n >> 1;
  int rg = tid >> 3, ct = tid & 7;
  int f0 = s * 32 + ct * 4;
  __shared__ short lists[1024];
  __shared__ float red[32][32];
  for (int i = tid; i < k; i += 256) lists[i] = listg[e * 1024 + i];
  __syncthreads();
  float a0 = 0.f, a1 = 0.f, a2 = 0.f, a3 = 0.f;
  if (isf32) {
    const float* cvf = (const float*)cv;
    for (int j = rg; j < k; j += 32) {
      int row = lists[j];
      float4 vv = *(const float4*)(cvf + ((size_t)e * 2048 + row) * HDIM + f0);
      a0 += vv.x; a1 += vv.y; a2 += vv.z; a3 += vv.w;
    }
  } else {
    const u16* cvh = (const u16*)cv;
    for (int j = rg; j < k; j += 32) {
      int row = lists[j];
      uint2 vv = *(const uint2*)(cvh + ((size_t)e * 2048 + row) * HDIM + f0);
      a0 += bf2f((u16)(vv.x & 0xffffu));
      a1 += bf2f((u16)(vv.x >> 16));
      a2 += bf2f((u16)(vv.y & 0xffffu));
      a3 += bf2f((u16)(vv.y >> 16));
    }
  }
  red[rg][ct * 4 + 0] = a0;
  red[rg][ct * 4 + 1] = a1;
  red[rg][ct * 4 + 2] = a2;
  red[rg][ct * 4 + 3] = a3;
  __syncthreads();
  if (tid < 32) {
    float sm = 0.f;
#pragma unroll
    for (int r = 0; r < 32; ++r) sm += red[r][tid];
    mean[(size_t)e * HDIM + s * 32 + tid] = sm / (float)k;
  }
}

// ---------------------------------------------------------------------------
// Pyramid cache stage 3 (unchanged, proven).
// ---------------------------------------------------------------------------
__global__ __launch_bounds__(256) void cache_finalize(
    const float* __restrict__ mean, const void* __restrict__ cla,
    const void* __restrict__ clb, const void* __restrict__ eb,
    float* __restrict__ ec, const int* __restrict__ flag) {
  int isf32 = *flag;
  int e = blockIdx.x, tid = threadIdx.x;
  __shared__ float tmp4[4];
  if (tid < 4) tmp4[tid] = 0.f;
  __syncthreads();
  int f0 = tid * 4;
  float m[4];
#pragma unroll
  for (int i = 0; i < 4; ++i) m[i] = mean[(size_t)e * HDIM + f0 + i];
#pragma unroll
  for (int r = 0; r < 4; ++r) {
    float pr = 0.f;
#pragma unroll
    for (int i = 0; i < 4; ++i)
      pr += m[i] * lde(cla, ((size_t)e * HDIM + f0 + i) * 4 + r, isf32);
    atomicAdd(&tmp4[r], pr);
  }
  __syncthreads();
#pragma unroll
  for (int i = 0; i < 4; ++i) {
    int f = f0 + i;
    float add = 0.f;
#pragma unroll
    for (int r = 0; r < 4; ++r)
      add += tmp4[r] * lde(clb, (size_t)e * 4 * HDIM + r * HDIM + f, isf32);
    ec[e * HDIM + f] = m[i] + LSCALE * add + lde(eb, (size_t)e * HDIM + f, isf32);
  }
}

// ---------------------------------------------------------------------------
// Build per-expert token lists (unchanged, proven).
// ---------------------------------------------------------------------------
__global__ __launch_bounds__(256) void route_build(
    const int* __restrict__ tope, u16* __restrict__ elist, int* __restrict__ ecnt) {
  int e = blockIdx.x;
  __shared__ int c;
  if (threadIdx.x == 0) c = 0;
  __syncthreads();
  for (int t = threadIdx.x; t < NTOK; t += 256) {
    int pe = tope[t];
    int e1 = pe & 255, e2 = (pe >> 8) & 255;
    if (e1 == e) { int p = atomicAdd(&c, 1); elist[e * NTOK + p] = (u16)t; }
    else if (e2 == e) { int p = atomicAdd(&c, 1); elist[e * NTOK + p] = (u16)(t | 0x8000); }
  }
  __syncthreads();
  if (threadIdx.x == 0) ecnt[e] = c;
}

// ---------------------------------------------------------------------------
// Gathered expert GEMM (unchanged, proven).
// ---------------------------------------------------------------------------
__global__ __launch_bounds__(256) void gemm_expert_gather(
    const u16* __restrict__ A, const u16* __restrict__ Bt,
    const float* __restrict__ topw, const u16* __restrict__ elist,
    const int* __restrict__ ecnt, const float* __restrict__ ec,
    float* __restrict__ slot0, float* __restrict__ slot1) {
  const int K = HDIM;
  int mc = blockIdx.x, n0 = blockIdx.y * 128, e = blockIdx.z;
  int cnt = ecnt[e];
  int r0 = mc * 64;
  if (r0 >= cnt) return;
  __shared__ alignas(16) u16 As[64 * 32];
  __shared__ alignas(16) u16 Bs[128 * 32];
  int tid = threadIdx.x, lane = tid & 63, wid = tid >> 6;
  int wm = wid >> 1, wn = wid & 1;
  int q = lane >> 4, lr = lane & 15;
  int srow = wid * 16 + (lane >> 2);
  int scol = (lane & 3) * 8;
  int li = r0 + srow; if (li >= cnt) li = r0;
  int tokme = elist[e * NTOK + li] & 2047;
  const u16* Ag = A + (size_t)tokme * K + scol;
  const u16* Bg = Bt + (size_t)e * K * HDIM + (size_t)(n0 + srow) * K + scol;
  u16* AsL = As + wid * 16 * 32;
  u16* BsL = Bs + wid * 16 * 32;
  f32x4 acc[2][4];
#pragma unroll
  for (int mi = 0; mi < 2; ++mi)
#pragma unroll
    for (int ni = 0; ni < 4; ++ni) acc[mi][ni] = (f32x4){0.f, 0.f, 0.f, 0.f};
  for (int kt = 0; kt < K / 32; ++kt) {
    __syncthreads();
    gload16(Ag + kt * 32, AsL);
    gload16(Bg + kt * 32, BsL);
    gload16(Bg + (size_t)64 * K + kt * 32, BsL + 64 * 32);
    __syncthreads();
    bf16x8 af[2], bfr[4];
#pragma unroll
    for (int mi = 0; mi < 2; ++mi)
      af[mi] = *(const bf16x8*)(As + (wm * 32 + mi * 16 + lr) * 32 + q * 8);
#pragma unroll
    for (int ni = 0; ni < 4; ++ni)
      bfr[ni] = *(const bf16x8*)(Bs + (wn * 64 + ni * 16 + lr) * 32 + q * 8);
#pragma unroll
    for (int mi = 0; mi < 2; ++mi)
#pragma unroll
      for (int ni = 0; ni < 4; ++ni)
        acc[mi][ni] = __builtin_amdgcn_mfma_f32_16x16x32_bf16(af[mi], bfr[ni], acc[mi][ni], 0, 0, 0);
  }
#pragma unroll
  for (int mi = 0; mi < 2; ++mi) {
#pragma unroll
    for (int r = 0; r < 4; ++r) {
      int lrow = wm * 32 + mi * 16 + q * 4 + r;
      int gi = r0 + lrow;
      if (gi >= cnt) continue;
      int ent = elist[e * NTOK + gi];
      int t2 = ent & 2047, sl = ent >> 15;
      float w = topw[t2 * 2 + sl];
      float* dst = sl ? slot1 : slot0;
#pragma unroll
      for (int ni = 0; ni < 4; ++ni) {
        int col = n0 + wn * 64 + ni * 16 + lr;
        dst[(size_t)t2 * HDIM + col] = w * (acc[mi][ni][r] + ec[e * HDIM + col]);
      }
    }
  }
}

// ---------------------------------------------------------------------------
// outh = f2bf(slot0 + slot1) (unchanged, proven).
// ---------------------------------------------------------------------------
__global__ __launch_bounds__(256) void combine_outh(
    const float* __restrict__ s0, const float* __restrict__ s1,
    u16* __restrict__ outh) {
  int i = blockIdx.x * 256 + threadIdx.x;
  float4 a = ((const float4*)s0)[i];
  float4 b = ((const float4*)s1)[i];
  u16 o[4] = { f2bf(a.x + b.x), f2bf(a.y + b.y), f2bf(a.z + b.z), f2bf(a.w + b.w) };
  ((uint2*)outh)[i] = *(uint2*)o;
}

// ---------------------------------------------------------------------------
// Vocab GEMM, 256x256 tile, BK=64, 512 threads (2M x 4N waves, 128x64/wave).
// R10 post-mortem: R4 (2 bar/phase) == R10 (1 bar/phase) == 672 TF -> the
// barrier skeleton is NOT the limiter; the per-phase lgkmcnt(0)+sched_barrier
// walls were (m141-style over-pinning: all reads forced complete before any
// MFMA, compiler's fine-grained lgkm interleave defeated). THIS round: same
// skeleton as R10 (proven correct twice), but intra-phase scheduling freed:
// no explicit lgkm wait (plain C++ ds_reads -> compiler emits per-MFMA
// counted lgkmcnt), no sched_barrier after vmcnt. Walls remain on BOTH
// sides of each s_barrier: reads can't hoist above (slab-staged guarantee),
// MFMAs+waits can't sink below (overwrite window).
// ---------------------------------------------------------------------------
#define VNT 16  // K/64

template<int VM2, int VM4, bool S12, bool S34>
__device__ __forceinline__ void vtile(
    int t, u16* lds, int wid,
    const u16* pA0, const u16* pA1, const u16* pB0, const u16* pB1,
    int aoff, int boff, f32x4 (&acc)[8][4]) {
  int buf = t & 1, obuf = buf ^ 1;
  const u16* As0 = lds + (buf * 2 + 0) * 8192;
  const u16* As1 = lds + (buf * 2 + 1) * 8192;
  const u16* Bs0 = lds + 32768 + (buf * 2 + 0) * 8192;
  const u16* Bs1 = lds + 32768 + (buf * 2 + 1) * 8192;
  bf16x8 af[4], bfr[4];
  // ---- phase 1: stage t+1.A.k1; read kk0 frags (B + A mi0-3); MFMA ----
  if (S12) {
    u16* d = lds + (obuf * 2 + 1) * 8192 + wid * 512;
    gload16(pA0 + (t + 1) * 64 + 32, d);
    gload16(pA1 + (t + 1) * 64 + 32, d + 4096);
  }
#pragma unroll
  for (int ni = 0; ni < 4; ++ni) bfr[ni] = *(const bf16x8*)(Bs0 + boff + ni * 512);
#pragma unroll
  for (int j = 0; j < 4; ++j) af[j] = *(const bf16x8*)(As0 + aoff + j * 512);
  __builtin_amdgcn_s_setprio(1);
#pragma unroll
  for (int j = 0; j < 4; ++j)
#pragma unroll
    for (int ni = 0; ni < 4; ++ni)
      acc[j][ni] = __builtin_amdgcn_mfma_f32_16x16x32_bf16(af[j], bfr[ni], acc[j][ni], 0, 0, 0);
  __builtin_amdgcn_s_setprio(0);
  SBAR();
  // ---- phase 2: stage t+1.B.k1; read A kk0 mi4-7; MFMA; vmcnt; bar ----
  if (S12) {
    u16* d = lds + 32768 + (obuf * 2 + 1) * 8192 + wid * 512;
    gload16(pB0 + (t + 1) * 64 + 32, d);
    gload16(pB1 + (t + 1) * 64 + 32, d + 4096);
  }
#pragma unroll
  for (int j = 0; j < 4; ++j) af[j] = *(const bf16x8*)(As0 + aoff + (4 + j) * 512);
  __builtin_amdgcn_s_setprio(1);
#pragma unroll
  for (int j = 0; j < 4; ++j)
#pragma unroll
    for (int ni = 0; ni < 4; ++ni)
      acc[4 + j][ni] = __builtin_amdgcn_mfma_f32_16x16x32_bf16(af[j], bfr[ni], acc[4 + j][ni], 0, 0, 0);
  __builtin_amdgcn_s_setprio(0);
  waitvm<VM2>();
  SBAR();
  // ---- phase 3: stage t+2.A.k0; read kk1 frags (B + A mi0-3); MFMA ----
  if (S34) {
    u16* d = lds + (buf * 2 + 0) * 8192 + wid * 512;
    gload16(pA0 + (t + 2) * 64, d);
    gload16(pA1 + (t + 2) * 64, d + 4096);
  }
#pragma unroll
  for (int ni = 0; ni < 4; ++ni) bfr[ni] = *(const bf16x8*)(Bs1 + boff + ni * 512);
#pragma unroll
  for (int j = 0; j < 4; ++j) af[j] = *(const bf16x8*)(As1 + aoff + j * 512);
  __builtin_amdgcn_s_setprio(1);
#pragma unroll
  for (int j = 0; j < 4; ++j)
#pragma unroll
    for (int ni = 0; ni < 4; ++ni)
      acc[j][ni] = __builtin_amdgcn_mfma_f32_16x16x32_bf16(af[j], bfr[ni], acc[j][ni], 0, 0, 0);
  __builtin_amdgcn_s_setprio(0);
  SBAR();
  // ---- phase 4: stage t+2.B.k0; read A kk1 mi4-7; MFMA; vmcnt; bar ----
  if (S34) {
    u16* d = lds + 32768 + (buf * 2 + 0) * 8192 + wid * 512;
    gload16(pB0 + (t + 2) * 64, d);
    gload16(pB1 + (t + 2) * 64, d + 4096);
  }
#pragma unroll
  for (int j = 0; j < 4; ++j) af[j] = *(const bf16x8*)(As1 + aoff + (4 + j) * 512);
  __builtin_amdgcn_s_setprio(1);
#pragma unroll
  for (int j = 0; j < 4; ++j)
#pragma unroll
    for (int ni = 0; ni < 4; ++ni)
      acc[4 + j][ni] = __builtin_amdgcn_mfma_f32_16x16x32_bf16(af[j], bfr[ni], acc[4 + j][ni], 0, 0, 0);
  __builtin_amdgcn_s_setprio(0);
  waitvm<VM4>();
  SBAR();
}

__global__ __launch_bounds__(512) void gemm_vocab(
    const u16* __restrict__ A, const u16* __restrict__ Bt,
    const void* __restrict__ bias, void* __restrict__ outp,
    int n0base, const int* __restrict__ flag) {
  int isf32 = *flag;
  const int K = HDIM, N = VDIM;
  int nwg = gridDim.x;
  int per = nwg >> 3;
  int newid = (blockIdx.x & 7) * per + (blockIdx.x >> 3);
  int bn = newid >> 3, bm = newid & 7;
  int m0 = bm * 256, n0l = bn * 256;
  __shared__ alignas(1024) u16 lds[65536];  // 128 KiB
  int tid = threadIdx.x, lane = tid & 63, wid = tid >> 6;
  int wm = wid >> 2, wn = wid & 3;
  int q = lane >> 4, lr = lane & 15;
  int colsw = (q ^ ((lr >> 1) & 3)) * 8;
  int aoff = wm * 4096 + lr * 32 + colsw;
  int boff = wn * 2048 + lr * 32 + colsw;
  int srl = lane >> 2;
  int ssw = ((lane & 3) ^ ((srl >> 1) & 3)) * 8;
  const u16* pA0 = A + (size_t)(m0 + wid * 16 + srl) * K + ssw;
  const u16* pA1 = A + (size_t)(m0 + (8 + wid) * 16 + srl) * K + ssw;
  const u16* pB0 = Bt + (size_t)(n0l + wid * 16 + srl) * K + ssw;
  const u16* pB1 = Bt + (size_t)(n0l + (8 + wid) * 16 + srl) * K + ssw;
  f32x4 acc[8][4];
#pragma unroll
  for (int mi = 0; mi < 8; ++mi)
#pragma unroll
    for (int ni = 0; ni < 4; ++ni) acc[mi][ni] = (f32x4){0.f, 0.f, 0.f, 0.f};
  {
    u16* dA0 = lds + 0 * 8192 + wid * 512;
    u16* dB0 = lds + 32768 + 0 * 8192 + wid * 512;
    u16* dA1 = lds + 1 * 8192 + wid * 512;
    u16* dB1 = lds + 32768 + 1 * 8192 + wid * 512;
    u16* eA0 = lds + 2 * 8192 + wid * 512;
    u16* eB0 = lds + 32768 + 2 * 8192 + wid * 512;
    gload16(pA0 + 0, dA0);       gload16(pA1 + 0, dA0 + 4096);
    gload16(pB0 + 0, dB0);       gload16(pB1 + 0, dB0 + 4096);
    gload16(pA0 + 32, dA1);      gload16(pA1 + 32, dA1 + 4096);
    gload16(pB0 + 32, dB1);      gload16(pB1 + 32, dB1 + 4096);
    gload16(pA0 + 64, eA0);      gload16(pA1 + 64, eA0 + 4096);
    gload16(pB0 + 64, eB0);      gload16(pB1 + 64, eB0 + 4096);
    asm volatile("s_waitcnt vmcnt(4)" ::: "memory");
    SBAR();
  }
#pragma unroll 2
  for (int t = 0; t < VNT - 2; ++t)
    vtile<8, 8, true, true>(t, lds, wid, pA0, pA1, pB0, pB1, aoff, boff, acc);
  vtile<8, 4, true, false>(VNT - 2, lds, wid, pA0, pA1, pB0, pB1, aoff, boff, acc);
  vtile<0, 0, false, false>(VNT - 1, lds, wid, pA0, pA1, pB0, pB1, aoff, boff, acc);
#pragma unroll
  for (int ni = 0; ni < 4; ++ni) {
    int col = n0base + n0l + wn * 64 + ni * 16 + lr;
    float vb = lde(bias, col, isf32);
#pragma unroll
    for (int mi = 0; mi < 8; ++mi) {
#pragma unroll
      for (int r = 0; r < 4; ++r) {
        int row = m0 + wm * 128 + mi * 16 + q * 4 + r;
        float val = acc[mi][ni][r] + vb;
        if (isf32) ((float*)outp)[(size_t)row * N + col] = val;
        else       ((u16*)outp)[(size_t)row * N + col] = f2bf(val);
      }
    }
  }
}

// ---------------------------------------------------------------------------
extern "C" void kernel_launch(void* const* d_in, const int* in_sizes, int n_in,
                              void* d_out, int out_size, void* d_ws, size_t ws_size,
                              hipStream_t stream) {
  const int*  x    = (const int*)d_in[0];
  const void* emb  = d_in[1];
  const void* gw   = d_in[2];
  const void* gb   = d_in[3];
  const void* ew   = d_in[4];
  const void* eb   = d_in[5];
  const void* ela  = d_in[6];
  const void* elb  = d_in[7];
  const void* cv   = d_in[8];
  const void* imp  = d_in[9];
  const void* cla  = d_in[10];
  const void* clb  = d_in[11];
  const void* vw   = d_in[12];
  const void* vb   = d_in[13];

  char* ws = (char*)d_ws;
  u16*   WeffT = (u16*)(ws);                  // 16,777,216 B
  u16*   h_bf  = (u16*)(ws + 16777216);       //  4,194,304 B
  u16*   outh  = (u16*)(ws + 20971520);       //  4,194,304 B
  float* ec    = (float*)(ws + 25165824);     //     32,768 B
  int*   flag  = (int*)(ws + 25198592);       //         64 B
  float* mean  = (float*)(ws + 25198656);     //     32,768 B
  short* listg = (short*)(ws + 25231424);     //     16,384 B
  int*   tope  = (int*)(ws + 25247808);       //      8,192 B
  float* topw  = (float*)(ws + 25256000);     //     16,384 B
  u16*   elist = (u16*)(ws + 25272384);       //     32,768 B
  int*   ecnt  = (int*)(ws + 25305152);       //         64 B
  float* slot0 = (float*)(ws + 25305216);     //  8,388,608 B
  float* slot1 = (float*)(ws + 33693824);     //  8,388,608 B
  u16*   chunk = (u16*)(ws + 42082432);       // vocab WT chunk (<= 64 MB)

  long long avail = (long long)ws_size - 42082432LL;
  long long cc = (avail > 0) ? (avail / (HDIM * 2)) : 0;
  cc &= ~255LL;
  if (cc > VDIM) cc = VDIM;
  if (cc < 256) cc = 256;
  int chunkcols = (int)cc;

  detect_dtype<<<dim3(1), 256, 0, stream>>>((const u16*)emb, flag);
  transpose_lora<<<dim3(HDIM / 64, HDIM / 64, NEXP), 256, 0, stream>>>(
      ew, WeffT, ela, elb, HDIM, HDIM, 1, 0, flag);
  embed_gate<<<dim3(NTOK), 256, 0, stream>>>(x, emb, gw, gb, h_bf, tope, topw, flag);
  cache_select<<<dim3(NEXP), 256, 0, stream>>>(imp, listg, flag);
  cache_pool<<<dim3(NEXP, 32), 256, 0, stream>>>(cv, listg, mean, flag);
  cache_finalize<<<dim3(NEXP), 256, 0, stream>>>(mean, cla, clb, eb, ec, flag);
  route_build<<<dim3(NEXP), 256, 0, stream>>>(tope, elist, ecnt);
  gemm_expert_gather<<<dim3(32, 8, NEXP), 256, 0, stream>>>(
      h_bf, WeffT, topw, elist, ecnt, ec, slot0, slot1);
  combine_outh<<<dim3(NTOK * HDIM / 4 / 256), 256, 0, stream>>>(slot0, slot1, outh);
  for (int c0 = 0; c0 < VDIM; c0 += chunkcols) {
    int nc = (VDIM - c0 < chunkcols) ? (VDIM - c0) : chunkcols;
    transpose_lora<<<dim3(HDIM / 64, nc / 64, 1), 256, 0, stream>>>(
        vw, chunk, nullptr, nullptr, HDIM, VDIM, 0, c0, flag);
    gemm_vocab<<<dim3((nc / 256) * 8), 512, 0, stream>>>(
        outh, chunk, vb, d_out, c0, flag);
  }
}